// Round 1
// baseline (2191.381 us; speedup 1.0000x reference)
//
#include <hip/hip_runtime.h>
#include <math.h>

#define HDIM 1024
#define NHEAD 16
#define HEADD 64
#define SEQLEN 2048
#define BATCH 4
#define MROWS (BATCH * SEQLEN)   // 8192
#define LN_EPS 1e-5f
#define INV_TEMP 2.0f            // scores / 0.5 == scores * 2

// ---------------------------------------------------------------------------
// Tiled fp32 GEMM: C = A(MxK) @ W^T + bias, W is [N,K] row-major (torch Linear).
// 64x64 tile, BK=16, 256 threads, 4x4 micro-tile per thread.
// HEAD_LAYOUT=1 writes C into [B, NH, S, HD] layout for the attention kernel.
// ---------------------------------------------------------------------------
template <int HEAD_LAYOUT>
__global__ __launch_bounds__(256) void gemm_bias_k(const float* __restrict__ A,
                                                   const float* __restrict__ W,
                                                   const float* __restrict__ bias,
                                                   float* __restrict__ C) {
  constexpr int BK = 16;
  __shared__ float As[BK][64 + 4];   // k-major, +4 pad
  __shared__ float Bs[BK][64 + 4];

  const int tid = threadIdx.x;
  const int tx = tid & 15;   // output cols tx*4 .. +3
  const int ty = tid >> 4;   // output rows ty*4 .. +3
  const int m0 = blockIdx.x << 6;
  const int n0 = blockIdx.y << 6;

  // staging: each thread loads one float4 of A and one of W per BK step
  const int lrow = tid >> 2;        // 0..63
  const int lk = (tid & 3) << 2;    // 0,4,8,12

  const float* Ap = A + (size_t)(m0 + lrow) * HDIM + lk;
  const float* Wp = W + (size_t)(n0 + lrow) * HDIM + lk;

  float acc[4][4] = {{0.f, 0.f, 0.f, 0.f}};

  for (int k0 = 0; k0 < HDIM; k0 += BK) {
    const float4 av = *reinterpret_cast<const float4*>(Ap + k0);
    const float4 wv = *reinterpret_cast<const float4*>(Wp + k0);
    As[lk + 0][lrow] = av.x;
    As[lk + 1][lrow] = av.y;
    As[lk + 2][lrow] = av.z;
    As[lk + 3][lrow] = av.w;
    Bs[lk + 0][lrow] = wv.x;
    Bs[lk + 1][lrow] = wv.y;
    Bs[lk + 2][lrow] = wv.z;
    Bs[lk + 3][lrow] = wv.w;
    __syncthreads();
#pragma unroll
    for (int kk = 0; kk < BK; ++kk) {
      const float4 a4 = *reinterpret_cast<const float4*>(&As[kk][ty << 2]);
      const float4 b4 = *reinterpret_cast<const float4*>(&Bs[kk][tx << 2]);
      const float ar[4] = {a4.x, a4.y, a4.z, a4.w};
      const float br[4] = {b4.x, b4.y, b4.z, b4.w};
#pragma unroll
      for (int i = 0; i < 4; ++i)
#pragma unroll
        for (int j = 0; j < 4; ++j) acc[i][j] = fmaf(ar[i], br[j], acc[i][j]);
    }
    __syncthreads();
  }

  const int c0 = n0 + (tx << 2);
  const float4 bv = *reinterpret_cast<const float4*>(&bias[c0]);
  const float bb[4] = {bv.x, bv.y, bv.z, bv.w};

  if (HEAD_LAYOUT) {
    // row m = b*SEQ + s ; col n = h*HD + d  ->  dst[((b*NH+h)*SEQ + s)*HD + d]
    const int b = m0 / SEQLEN;                 // tile never spans batches (64 | 2048)
    const int s0 = (m0 % SEQLEN) + (ty << 2);
    const int h = n0 >> 6;                     // BN == HEADD == 64
    float* dst = C + ((size_t)(b * NHEAD + h) * SEQLEN + s0) * HEADD + (tx << 2);
#pragma unroll
    for (int i = 0; i < 4; ++i) {
      float4 o;
      o.x = acc[i][0] + bb[0];
      o.y = acc[i][1] + bb[1];
      o.z = acc[i][2] + bb[2];
      o.w = acc[i][3] + bb[3];
      *reinterpret_cast<float4*>(dst + i * HEADD) = o;
    }
  } else {
    float* dst = C + (size_t)(m0 + (ty << 2)) * HDIM + c0;
#pragma unroll
    for (int i = 0; i < 4; ++i) {
      float4 o;
      o.x = acc[i][0] + bb[0];
      o.y = acc[i][1] + bb[1];
      o.z = acc[i][2] + bb[2];
      o.w = acc[i][3] + bb[3];
      *reinterpret_cast<float4*>(dst + i * HDIM) = o;
    }
  }
}

// ---------------------------------------------------------------------------
// Flash-style fp32 attention. Block = one (b, h, 64-row Q tile); 256 threads.
// K is staged transposed (Kt[d][key]) so the QK^T inner loop reads contiguous
// float4 fragments (2-way bank aliasing only). Online softmax, P staged in LDS
// for the PV product. Output written in [B, S, H] layout.
// ---------------------------------------------------------------------------
__global__ __launch_bounds__(256) void attn_k(const float* __restrict__ Q,
                                              const float* __restrict__ K,
                                              const float* __restrict__ V,
                                              float* __restrict__ O) {
  __shared__ float Qt[HEADD][64 + 4];  // Qt[d][row]
  __shared__ float Kt[HEADD][64 + 4];  // Kt[d][key]
  __shared__ float Vs[64][HEADD + 4];  // Vs[key][d]
  __shared__ float Ps[64][64 + 4];     // Ps[row][key]

  const int tid = threadIdx.x;
  const int tx = tid & 15;   // key-cols / out-dims tx*4..+3
  const int ty = tid >> 4;   // q-rows ty*4..+3
  const int qt = blockIdx.x; // 0..31
  const int bh = blockIdx.y; // 0..63  (b*NH + h)

  const float* Qb = Q + ((size_t)bh * SEQLEN + (qt << 6)) * HEADD;
  const float* Kb = K + (size_t)bh * SEQLEN * HEADD;
  const float* Vb = V + (size_t)bh * SEQLEN * HEADD;

  // stage Q tile transposed (once)
  for (int t = tid; t < 64 * 16; t += 256) {
    const int r = t >> 4, c = (t & 15) << 2;
    const float4 v = *reinterpret_cast<const float4*>(&Qb[r * HEADD + c]);
    Qt[c + 0][r] = v.x;
    Qt[c + 1][r] = v.y;
    Qt[c + 2][r] = v.z;
    Qt[c + 3][r] = v.w;
  }

  float m_run[4], l_run[4];
  float o_acc[4][4] = {{0.f, 0.f, 0.f, 0.f}};
#pragma unroll
  for (int i = 0; i < 4; ++i) {
    m_run[i] = -1e30f;
    l_run[i] = 0.f;
  }
  __syncthreads();

  for (int kt = 0; kt < SEQLEN / 64; ++kt) {
    const float* Kp = Kb + (size_t)(kt << 6) * HEADD;
    const float* Vp = Vb + (size_t)(kt << 6) * HEADD;
    for (int t = tid; t < 64 * 16; t += 256) {
      const int r = t >> 4, c = (t & 15) << 2;
      const float4 kv = *reinterpret_cast<const float4*>(&Kp[r * HEADD + c]);
      Kt[c + 0][r] = kv.x;
      Kt[c + 1][r] = kv.y;
      Kt[c + 2][r] = kv.z;
      Kt[c + 3][r] = kv.w;
      *reinterpret_cast<float4*>(&Vs[r][c]) =
          *reinterpret_cast<const float4*>(&Vp[r * HEADD + c]);
    }
    __syncthreads();

    // S = Q K^T (tile), 4x4 per thread
    float s[4][4] = {{0.f, 0.f, 0.f, 0.f}};
#pragma unroll 8
    for (int d = 0; d < HEADD; ++d) {
      const float4 qv = *reinterpret_cast<const float4*>(&Qt[d][ty << 2]);
      const float4 kv = *reinterpret_cast<const float4*>(&Kt[d][tx << 2]);
      const float qr[4] = {qv.x, qv.y, qv.z, qv.w};
      const float kr[4] = {kv.x, kv.y, kv.z, kv.w};
#pragma unroll
      for (int i = 0; i < 4; ++i)
#pragma unroll
        for (int j = 0; j < 4; ++j) s[i][j] = fmaf(qr[i], kr[j], s[i][j]);
    }

    // online softmax (row groups = 16 contiguous lanes within a wave)
#pragma unroll
    for (int i = 0; i < 4; ++i) {
      float p[4];
#pragma unroll
      for (int j = 0; j < 4; ++j) p[j] = s[i][j] * INV_TEMP;
      float mx = fmaxf(fmaxf(p[0], p[1]), fmaxf(p[2], p[3]));
#pragma unroll
      for (int off = 1; off < 16; off <<= 1) mx = fmaxf(mx, __shfl_xor(mx, off));
      const float m_new = fmaxf(m_run[i], mx);
      const float corr = __expf(m_run[i] - m_new);
      float psum = 0.f;
#pragma unroll
      for (int j = 0; j < 4; ++j) {
        p[j] = __expf(p[j] - m_new);
        psum += p[j];
      }
#pragma unroll
      for (int off = 1; off < 16; off <<= 1) psum += __shfl_xor(psum, off);
      l_run[i] = l_run[i] * corr + psum;
      m_run[i] = m_new;
#pragma unroll
      for (int j = 0; j < 4; ++j) o_acc[i][j] *= corr;
      float4 p4;
      p4.x = p[0]; p4.y = p[1]; p4.z = p[2]; p4.w = p[3];
      *reinterpret_cast<float4*>(&Ps[(ty << 2) + i][tx << 2]) = p4;
    }
    __syncthreads();

    // O += P @ V
#pragma unroll 8
    for (int k = 0; k < 64; ++k) {
      const float4 vv = *reinterpret_cast<const float4*>(&Vs[k][tx << 2]);
      const float vr[4] = {vv.x, vv.y, vv.z, vv.w};
#pragma unroll
      for (int i = 0; i < 4; ++i) {
        const float pr = Ps[(ty << 2) + i][k];
#pragma unroll
        for (int j = 0; j < 4; ++j) o_acc[i][j] = fmaf(pr, vr[j], o_acc[i][j]);
      }
    }
    __syncthreads();
  }

  // epilogue: divide by l, write to [B, S, H]
  const int b = bh >> 4;
  const int h = bh & 15;
#pragma unroll
  for (int i = 0; i < 4; ++i) {
    const float inv_l = 1.0f / l_run[i];
    const int srow = (qt << 6) + (ty << 2) + i;
    float* dst = O + ((size_t)b * SEQLEN + srow) * HDIM + (h << 6) + (tx << 2);
    float4 o;
    o.x = o_acc[i][0] * inv_l;
    o.y = o_acc[i][1] * inv_l;
    o.z = o_acc[i][2] * inv_l;
    o.w = o_acc[i][3] * inv_l;
    *reinterpret_cast<float4*>(dst) = o;
  }
}

// ---------------------------------------------------------------------------
// Fused ReLU + LayerNorm over rows of 1024. One block (256 thr) per row.
// ---------------------------------------------------------------------------
__global__ __launch_bounds__(256) void relu_ln_k(const float* __restrict__ X,
                                                 const float* __restrict__ g,
                                                 const float* __restrict__ bta,
                                                 float* __restrict__ out) {
  __shared__ float red[8];
  const int row = blockIdx.x;
  const int tid = threadIdx.x;
  const int c = tid << 2;

  const float4 v = *reinterpret_cast<const float4*>(&X[(size_t)row * HDIM + c]);
  float x[4] = {fmaxf(v.x, 0.f), fmaxf(v.y, 0.f), fmaxf(v.z, 0.f), fmaxf(v.w, 0.f)};
  float sum = x[0] + x[1] + x[2] + x[3];
  float ss = x[0] * x[0] + x[1] * x[1] + x[2] * x[2] + x[3] * x[3];
#pragma unroll
  for (int off = 1; off < 64; off <<= 1) {
    sum += __shfl_xor(sum, off);
    ss += __shfl_xor(ss, off);
  }
  const int wid = tid >> 6;
  if ((tid & 63) == 0) {
    red[wid] = sum;
    red[4 + wid] = ss;
  }
  __syncthreads();
  sum = red[0] + red[1] + red[2] + red[3];
  ss = red[4] + red[5] + red[6] + red[7];
  const float mean = sum * (1.0f / HDIM);
  const float var = ss * (1.0f / HDIM) - mean * mean;
  const float rstd = rsqrtf(var + LN_EPS);

  const float4 gv = *reinterpret_cast<const float4*>(&g[c]);
  const float4 bv = *reinterpret_cast<const float4*>(&bta[c]);
  float4 o;
  o.x = (x[0] - mean) * rstd * gv.x + bv.x;
  o.y = (x[1] - mean) * rstd * gv.y + bv.y;
  o.z = (x[2] - mean) * rstd * gv.z + bv.z;
  o.w = (x[3] - mean) * rstd * gv.w + bv.w;
  *reinterpret_cast<float4*>(&out[(size_t)row * HDIM + c]) = o;
}

// ---------------------------------------------------------------------------
// Launch. ws layout: Q | K | V | attn  (4 x 32 MB = 128 MB).
// proj output aliases Q (attention has completed by then; stream-ordered).
// ---------------------------------------------------------------------------
extern "C" void kernel_launch(void* const* d_in, const int* in_sizes, int n_in,
                              void* d_out, int out_size, void* d_ws, size_t ws_size,
                              hipStream_t stream) {
  const float* feat = (const float*)d_in[0];
  const float* qw = (const float*)d_in[1];
  const float* qb = (const float*)d_in[2];
  const float* kw = (const float*)d_in[3];
  const float* kb = (const float*)d_in[4];
  const float* vw = (const float*)d_in[5];
  const float* vb = (const float*)d_in[6];
  const float* ow = (const float*)d_in[7];
  const float* ob = (const float*)d_in[8];
  const float* ln_g = (const float*)d_in[9];
  const float* ln_b = (const float*)d_in[10];

  const size_t elems = (size_t)MROWS * HDIM;  // 8M floats = 32 MB
  float* Qd = (float*)d_ws;
  float* Kd = Qd + elems;
  float* Vd = Kd + elems;
  float* attn = Vd + elems;
  float* proj = Qd;  // reuse

  const dim3 gg(MROWS / 64, HDIM / 64);
  gemm_bias_k<1><<<gg, 256, 0, stream>>>(feat, qw, qb, Qd);
  gemm_bias_k<1><<<gg, 256, 0, stream>>>(feat, kw, kb, Kd);
  gemm_bias_k<1><<<gg, 256, 0, stream>>>(feat, vw, vb, Vd);
  attn_k<<<dim3(SEQLEN / 64, BATCH * NHEAD), 256, 0, stream>>>(Qd, Kd, Vd, attn);
  gemm_bias_k<0><<<gg, 256, 0, stream>>>(attn, ow, ob, proj);
  relu_ln_k<<<MROWS, 256, 0, stream>>>(proj, ln_g, ln_b, (float*)d_out);
}

// Round 2
// 655.062 us; speedup vs baseline: 3.3453x; 3.3453x over previous
//
#include <hip/hip_runtime.h>
#include <math.h>

#define HDIM 1024
#define NHEAD 16
#define HEADD 64
#define SEQLEN 2048
#define BATCH 4
#define MROWS (BATCH * SEQLEN)  // 8192
#define LN_EPS 1e-5f

typedef float f32x4 __attribute__((ext_vector_type(4)));
typedef short s16x8 __attribute__((ext_vector_type(8)));
typedef __bf16 bf16x4 __attribute__((ext_vector_type(4)));

#define MFMA16(a, b, c) __builtin_amdgcn_mfma_f32_16x16x32_bf16((a), (b), (c), 0, 0, 0)

__device__ __forceinline__ void load_lds16(const __bf16* g, __bf16* l) {
  __builtin_amdgcn_global_load_lds((const __attribute__((address_space(1))) void*)g,
                                   (__attribute__((address_space(3))) void*)l, 16, 0, 0);
}

// ---------------------------------------------------------------------------
// fp32 -> bf16 (hi, lo) split, 4 elems/thread
// ---------------------------------------------------------------------------
__global__ __launch_bounds__(256) void split_k(const float* __restrict__ src,
                                               __bf16* __restrict__ h,
                                               __bf16* __restrict__ l, int n4) {
  int i = blockIdx.x * blockDim.x + threadIdx.x;
  if (i >= n4) return;
  float4 v = reinterpret_cast<const float4*>(src)[i];
  bf16x4 hv, lv;
  hv[0] = (__bf16)v.x; hv[1] = (__bf16)v.y; hv[2] = (__bf16)v.z; hv[3] = (__bf16)v.w;
  lv[0] = (__bf16)(v.x - (float)hv[0]);
  lv[1] = (__bf16)(v.y - (float)hv[1]);
  lv[2] = (__bf16)(v.z - (float)hv[2]);
  lv[3] = (__bf16)(v.w - (float)hv[3]);
  reinterpret_cast<bf16x4*>(h)[i] = hv;
  reinterpret_cast<bf16x4*>(l)[i] = lv;
}

// ---------------------------------------------------------------------------
// Split-bf16 3-pass MFMA GEMM: C = A @ W^T + bias.
// A: [8192][1024] (hi,lo bf16), W: [1024][1024] (hi,lo bf16).
// 128x128 tile, BK=32, 4 waves (2x2), 16x16x32 MFMA, global_load_lds staging.
// EPI: 0 = head-layout bf16 hi/lo (Q,K) ; 1 = transposed Vt bf16 hi ; 2 = fp32.
// ---------------------------------------------------------------------------
template <int EPI>
__global__ __launch_bounds__(256, 2) void gemm3p_k(
    const __bf16* __restrict__ AH, const __bf16* __restrict__ AL,
    const __bf16* __restrict__ BH, const __bf16* __restrict__ BL,
    const float* __restrict__ bias, __bf16* __restrict__ CH,
    __bf16* __restrict__ CL, float* __restrict__ CF) {
  // smem layout (bf16 elems): AH:buf*4096, AL:8192+, BH:16384+, BL:24576+
  __shared__ __bf16 smem[32768];

  const int tid = threadIdx.x;
  const int lane = tid & 63;
  const int w = tid >> 6;
  const int fr = lane & 15;
  const int g = lane >> 4;
  const int wm = w >> 1, wn = w & 1;
  const int m0 = blockIdx.x << 7;
  const int n0 = blockIdx.y << 7;

#define GSTAGE(buf, kt)                                                       \
  do {                                                                        \
    const int ke_ = (kt) * 32 + (lane & 3) * 8;                               \
    _Pragma("unroll") for (int c_ = 0; c_ < 2; ++c_) {                        \
      const int rr_ = 32 * w + 16 * c_ + (lane >> 2);                         \
      const int lo_ = (32 * w + 16 * c_) * 32;                                \
      load_lds16(AH + (size_t)(m0 + rr_) * HDIM + ke_, &smem[(buf)*4096 + lo_]); \
      load_lds16(AL + (size_t)(m0 + rr_) * HDIM + ke_, &smem[8192 + (buf)*4096 + lo_]); \
      load_lds16(BH + (size_t)(n0 + rr_) * HDIM + ke_, &smem[16384 + (buf)*4096 + lo_]); \
      load_lds16(BL + (size_t)(n0 + rr_) * HDIM + ke_, &smem[24576 + (buf)*4096 + lo_]); \
    }                                                                         \
  } while (0)

  f32x4 acc[4][4] = {};

  GSTAGE(0, 0);
  __syncthreads();

  for (int kt = 0; kt < HDIM / 32; ++kt) {
    const int buf = kt & 1;
    if (kt + 1 < HDIM / 32) GSTAGE(buf ^ 1, kt + 1);

    s16x8 aH[4], aL[4], bH[4], bL[4];
#pragma unroll
    for (int mi = 0; mi < 4; ++mi) {
      const int off = (wm * 64 + mi * 16 + fr) * 32 + g * 8;
      aH[mi] = *reinterpret_cast<const s16x8*>(&smem[buf * 4096 + off]);
      aL[mi] = *reinterpret_cast<const s16x8*>(&smem[8192 + buf * 4096 + off]);
    }
#pragma unroll
    for (int ni = 0; ni < 4; ++ni) {
      const int off = (wn * 64 + ni * 16 + fr) * 32 + g * 8;
      bH[ni] = *reinterpret_cast<const s16x8*>(&smem[16384 + buf * 4096 + off]);
      bL[ni] = *reinterpret_cast<const s16x8*>(&smem[24576 + buf * 4096 + off]);
    }
#pragma unroll
    for (int mi = 0; mi < 4; ++mi)
#pragma unroll
      for (int ni = 0; ni < 4; ++ni) {
        acc[mi][ni] = MFMA16(aH[mi], bH[ni], acc[mi][ni]);
        acc[mi][ni] = MFMA16(aH[mi], bL[ni], acc[mi][ni]);
        acc[mi][ni] = MFMA16(aL[mi], bH[ni], acc[mi][ni]);
      }
    __syncthreads();
  }

  float bv[4];
#pragma unroll
  for (int ni = 0; ni < 4; ++ni) bv[ni] = bias[n0 + wn * 64 + ni * 16 + fr];

  if (EPI == 0) {  // head layout [B,NH,S,HD], bf16 hi/lo
#pragma unroll
    for (int mi = 0; mi < 4; ++mi)
#pragma unroll
      for (int ni = 0; ni < 4; ++ni)
#pragma unroll
        for (int r = 0; r < 4; ++r) {
          const float v = acc[mi][ni][r] + bv[ni];
          const int m = m0 + wm * 64 + mi * 16 + 4 * g + r;
          const int n = n0 + wn * 64 + ni * 16 + fr;
          const int b = m >> 11, s = m & 2047, h = n >> 6, d = n & 63;
          const size_t o = ((size_t)(b * NHEAD + h) * SEQLEN + s) * HEADD + d;
          const __bf16 hb = (__bf16)v;
          CH[o] = hb;
          CL[o] = (__bf16)(v - (float)hb);
        }
  } else if (EPI == 2) {  // plain fp32 [M][H]
#pragma unroll
    for (int mi = 0; mi < 4; ++mi)
#pragma unroll
      for (int ni = 0; ni < 4; ++ni)
#pragma unroll
        for (int r = 0; r < 4; ++r) {
          const int m = m0 + wm * 64 + mi * 16 + 4 * g + r;
          const int n = n0 + wn * 64 + ni * 16 + fr;
          CF[(size_t)m * HDIM + n] = acc[mi][ni][r] + bv[ni];
        }
  } else {  // EPI == 1: transposed Vt [B,NH,HD,S] bf16 hi via LDS transpose
    __syncthreads();
    // write transposed into smem[0..16384) = Tv[128 n][128 m], 16B-chunk XOR swz
#pragma unroll
    for (int mi = 0; mi < 4; ++mi)
#pragma unroll
      for (int ni = 0; ni < 4; ++ni)
#pragma unroll
        for (int r = 0; r < 4; ++r) {
          const float v = acc[mi][ni][r] + bv[ni];
          const int nl = wn * 64 + ni * 16 + fr;
          const int ml = wm * 64 + mi * 16 + 4 * g + r;
          smem[nl * 128 + (((ml >> 3) ^ (nl & 7)) << 3) + (ml & 7)] = (__bf16)v;
        }
    __syncthreads();
    const int nl = tid >> 1, mh = tid & 1;
    const int b = m0 >> 11, s0 = m0 & 2047;
    const int gn = n0 + nl, h = gn >> 6, d = gn & 63;
#pragma unroll
    for (int j = 0; j < 8; ++j) {
      const int cm = mh * 8 + j;
      s16x8 vv = *reinterpret_cast<const s16x8*>(&smem[nl * 128 + ((cm ^ (nl & 7)) << 3)]);
      const size_t o = ((size_t)((b * NHEAD + h) * HEADD + d)) * SEQLEN + s0 + cm * 8;
      *reinterpret_cast<s16x8*>(&CH[o]) = vv;
    }
  }
#undef GSTAGE
}

// ---------------------------------------------------------------------------
// Flash attention, MFMA, split-bf16. Block = (bh, 64-q-tile); 4 waves x 16 q.
// Q hi/lo in regs; K hi/lo + Vt(hi) staged w/ pre-swizzled global_load_lds;
// in-register wave-parallel online softmax; P hi/lo round-trip through LDS.
// ---------------------------------------------------------------------------
__global__ __launch_bounds__(256, 2) void attn3p_k(
    const __bf16* __restrict__ QH, const __bf16* __restrict__ QL,
    const __bf16* __restrict__ KH, const __bf16* __restrict__ KL,
    const __bf16* __restrict__ VT, __bf16* __restrict__ OH,
    __bf16* __restrict__ OL) {
  // smem (bf16 elems): KH:buf*4096, KL:8192+buf*4096, V:16384+buf*4096,
  //                    PsH:24576, PsL:28672
  __shared__ __bf16 smem[32768];

  const int tid = threadIdx.x;
  const int lane = tid & 63;
  const int w = tid >> 6;
  const int fr = lane & 15;
  const int g = lane >> 4;

  // XCD-aware block swizzle: xcd gets 8 bh x all q-tiles
  const int blk = blockIdx.x;
  const int xcd = blk & 7, idx = blk >> 3;
  const int bh = xcd * 8 + (idx & 7);
  const int qt = idx >> 3;
  const int q0 = qt << 6;
  const size_t bhO = (size_t)bh * SEQLEN * HEADD;

  // Q fragments (A-operand): row = fr, k(d) = ks*32 + g*8 + i
  s16x8 qHf[2], qLf[2];
  {
    const size_t qoff = bhO + (size_t)(q0 + w * 16 + fr) * HEADD;
#pragma unroll
    for (int ks = 0; ks < 2; ++ks) {
      qHf[ks] = *reinterpret_cast<const s16x8*>(&QH[qoff + ks * 32 + g * 8]);
      qLf[ks] = *reinterpret_cast<const s16x8*>(&QL[qoff + ks * 32 + g * 8]);
    }
  }

#define ASTAGE(buf, kt)                                                        \
  do {                                                                         \
    const int kv0_ = (kt) * 64;                                                \
    const int rsub_ = lane >> 3;                                               \
    const int ch_ = (lane & 7) ^ rsub_;                                        \
    _Pragma("unroll") for (int i_ = 0; i_ < 6; ++i_) {                         \
      const int L_ = w * 6 + i_;                                               \
      const int t_ = L_ >> 3, sub_ = L_ & 7;                                   \
      __bf16* lp_ = &smem[t_ * 8192 + (buf)*4096 + sub_ * 512];                \
      if (t_ < 2) {                                                            \
        const __bf16* base_ = (t_ == 0) ? KH : KL;                             \
        load_lds16(base_ + bhO + (size_t)(kv0_ + sub_ * 8 + rsub_) * HEADD + ch_ * 8, lp_); \
      } else {                                                                 \
        load_lds16(VT + ((size_t)bh * HEADD + sub_ * 8 + rsub_) * SEQLEN + kv0_ + ch_ * 8, lp_); \
      }                                                                        \
    }                                                                          \
  } while (0)

  f32x4 oacc[4] = {};
  float m_run[4], l_run[4];
#pragma unroll
  for (int r = 0; r < 4; ++r) {
    m_run[r] = -1e30f;
    l_run[r] = 0.f;
  }

  ASTAGE(0, 0);
  __syncthreads();

  for (int kt = 0; kt < SEQLEN / 64; ++kt) {
    const int buf = kt & 1;
    if (kt + 1 < SEQLEN / 64) ASTAGE(buf ^ 1, kt + 1);

    // ---- S = Q K^T (3-pass split) ----
    f32x4 sf[4] = {};
#pragma unroll
    for (int ks = 0; ks < 2; ++ks)
#pragma unroll
      for (int ni = 0; ni < 4; ++ni) {
        const int row = ni * 16 + fr;
        const int off = row * 64 + (((ks * 4 + g) ^ (fr & 7)) << 3);
        s16x8 kh = *reinterpret_cast<const s16x8*>(&smem[buf * 4096 + off]);
        s16x8 kl = *reinterpret_cast<const s16x8*>(&smem[8192 + buf * 4096 + off]);
        sf[ni] = MFMA16(qHf[ks], kh, sf[ni]);
        sf[ni] = MFMA16(qHf[ks], kl, sf[ni]);
        sf[ni] = MFMA16(qLf[ks], kh, sf[ni]);
      }

    // ---- online softmax (rows q = w*16 + 4g + r, cols across 16-lane group) ----
    float pb[4][4];
#pragma unroll
    for (int r = 0; r < 4; ++r) {
      float mx = -1e30f;
#pragma unroll
      for (int ni = 0; ni < 4; ++ni) {
        pb[ni][r] = sf[ni][r] * 2.0f;  // / TEMP(0.5)
        mx = fmaxf(mx, pb[ni][r]);
      }
#pragma unroll
      for (int off = 1; off < 16; off <<= 1) mx = fmaxf(mx, __shfl_xor(mx, off));
      const float m_new = fmaxf(m_run[r], mx);
      const float corr = __expf(m_run[r] - m_new);
      float psum = 0.f;
#pragma unroll
      for (int ni = 0; ni < 4; ++ni) {
        pb[ni][r] = __expf(pb[ni][r] - m_new);
        psum += pb[ni][r];
      }
#pragma unroll
      for (int off = 1; off < 16; off <<= 1) psum += __shfl_xor(psum, off);
      l_run[r] = l_run[r] * corr + psum;
      m_run[r] = m_new;
#pragma unroll
      for (int ni = 0; ni < 4; ++ni) oacc[ni][r] *= corr;
    }

    // ---- write P (hi/lo) to LDS, swizzled ----
#pragma unroll
    for (int ni = 0; ni < 4; ++ni)
#pragma unroll
      for (int r = 0; r < 4; ++r) {
        const int q = w * 16 + 4 * g + r;
        const int kv = ni * 16 + fr;
        const int flat = q * 64 + (((kv >> 3) ^ (q & 7)) << 3) + (kv & 7);
        const float p = pb[ni][r];
        const __bf16 ph = (__bf16)p;
        smem[24576 + flat] = ph;
        smem[28672 + flat] = (__bf16)(p - (float)ph);
      }

    // ---- O += P @ V (2-pass: Phi*Vh + Plo*Vh) ----
#pragma unroll
    for (int ks = 0; ks < 2; ++ks) {
      const int q = w * 16 + fr;
      const int poff = q * 64 + (((ks * 4 + g) ^ (fr & 7)) << 3);
      s16x8 pH = *reinterpret_cast<const s16x8*>(&smem[24576 + poff]);
      s16x8 pL = *reinterpret_cast<const s16x8*>(&smem[28672 + poff]);
#pragma unroll
      for (int ni = 0; ni < 4; ++ni) {
        const int d = ni * 16 + fr;
        const int voff = d * 64 + (((ks * 4 + g) ^ (fr & 7)) << 3);
        s16x8 vf = *reinterpret_cast<const s16x8*>(&smem[16384 + buf * 4096 + voff]);
        oacc[ni] = MFMA16(pH, vf, oacc[ni]);
        oacc[ni] = MFMA16(pL, vf, oacc[ni]);
      }
    }
    __syncthreads();
  }

  // ---- epilogue: normalize, write attn [B,S,H] bf16 hi/lo ----
  const int b = bh >> 4, h = bh & 15;
#pragma unroll
  for (int r = 0; r < 4; ++r) {
    const float inv = 1.0f / l_run[r];
    const int srow = q0 + w * 16 + 4 * g + r;
#pragma unroll
    for (int ni = 0; ni < 4; ++ni) {
      const float v = oacc[ni][r] * inv;
      const size_t o = ((size_t)b * SEQLEN + srow) * HDIM + h * 64 + ni * 16 + fr;
      const __bf16 hb = (__bf16)v;
      OH[o] = hb;
      OL[o] = (__bf16)(v - (float)hb);
    }
  }
#undef ASTAGE
}

// ---------------------------------------------------------------------------
// Fused ReLU + LayerNorm over rows of 1024. One block (256 thr) per row.
// ---------------------------------------------------------------------------
__global__ __launch_bounds__(256) void relu_ln_k(const float* __restrict__ X,
                                                 const float* __restrict__ gam,
                                                 const float* __restrict__ bta,
                                                 float* __restrict__ out) {
  __shared__ float red[8];
  const int row = blockIdx.x;
  const int tid = threadIdx.x;
  const int c = tid << 2;

  const float4 v = *reinterpret_cast<const float4*>(&X[(size_t)row * HDIM + c]);
  float x[4] = {fmaxf(v.x, 0.f), fmaxf(v.y, 0.f), fmaxf(v.z, 0.f), fmaxf(v.w, 0.f)};
  float sum = x[0] + x[1] + x[2] + x[3];
  float ss = x[0] * x[0] + x[1] * x[1] + x[2] * x[2] + x[3] * x[3];
#pragma unroll
  for (int off = 1; off < 64; off <<= 1) {
    sum += __shfl_xor(sum, off);
    ss += __shfl_xor(ss, off);
  }
  const int wid = tid >> 6;
  if ((tid & 63) == 0) {
    red[wid] = sum;
    red[4 + wid] = ss;
  }
  __syncthreads();
  sum = red[0] + red[1] + red[2] + red[3];
  ss = red[4] + red[5] + red[6] + red[7];
  const float mean = sum * (1.0f / HDIM);
  const float var = ss * (1.0f / HDIM) - mean * mean;
  const float rstd = rsqrtf(var + LN_EPS);

  const float4 gv = *reinterpret_cast<const float4*>(&gam[c]);
  const float4 bv = *reinterpret_cast<const float4*>(&bta[c]);
  float4 o;
  o.x = (x[0] - mean) * rstd * gv.x + bv.x;
  o.y = (x[1] - mean) * rstd * gv.y + bv.y;
  o.z = (x[2] - mean) * rstd * gv.z + bv.z;
  o.w = (x[3] - mean) * rstd * gv.w + bv.w;
  *reinterpret_cast<float4*>(&out[(size_t)row * HDIM + c]) = o;
}

// ---------------------------------------------------------------------------
// Launch. ws (128 MB):
//  [0,16M): wts hi (qw,kw,vw,ow @2MB) + wts lo (@2MB each)
//  [16,48M): QH,QL        -> later proj fp32 (32MB)
//  [48,80M): KH,KL
//  [80,96M): VtH
//  [96,128M): featH,featL -> later attnH,attnL
// ---------------------------------------------------------------------------
extern "C" void kernel_launch(void* const* d_in, const int* in_sizes, int n_in,
                              void* d_out, int out_size, void* d_ws, size_t ws_size,
                              hipStream_t stream) {
  const float* feat = (const float*)d_in[0];
  const float* qw = (const float*)d_in[1];
  const float* qb = (const float*)d_in[2];
  const float* kw = (const float*)d_in[3];
  const float* kb = (const float*)d_in[4];
  const float* vw = (const float*)d_in[5];
  const float* vb = (const float*)d_in[6];
  const float* ow = (const float*)d_in[7];
  const float* ob = (const float*)d_in[8];
  const float* ln_g = (const float*)d_in[9];
  const float* ln_b = (const float*)d_in[10];

  char* ws = (char*)d_ws;
  const size_t MB = 1u << 20;
  __bf16* qwH = (__bf16*)(ws + 0 * MB);
  __bf16* kwH = (__bf16*)(ws + 2 * MB);
  __bf16* vwH = (__bf16*)(ws + 4 * MB);
  __bf16* owH = (__bf16*)(ws + 6 * MB);
  __bf16* qwL = (__bf16*)(ws + 8 * MB);
  __bf16* kwL = (__bf16*)(ws + 10 * MB);
  __bf16* vwL = (__bf16*)(ws + 12 * MB);
  __bf16* owL = (__bf16*)(ws + 14 * MB);
  __bf16* QHp = (__bf16*)(ws + 16 * MB);
  __bf16* QLp = (__bf16*)(ws + 32 * MB);
  __bf16* KHp = (__bf16*)(ws + 48 * MB);
  __bf16* KLp = (__bf16*)(ws + 64 * MB);
  __bf16* VTp = (__bf16*)(ws + 80 * MB);
  __bf16* ftH = (__bf16*)(ws + 96 * MB);
  __bf16* ftL = (__bf16*)(ws + 112 * MB);
  __bf16* atH = ftH;  // reuse after feat dead
  __bf16* atL = ftL;
  float* proj = (float*)(ws + 16 * MB);  // reuse Q region after attention

  // splits
  split_k<<<(MROWS * HDIM / 4 + 255) / 256, 256, 0, stream>>>(feat, ftH, ftL, MROWS * HDIM / 4);
  split_k<<<(HDIM * HDIM / 4 + 255) / 256, 256, 0, stream>>>(qw, qwH, qwL, HDIM * HDIM / 4);
  split_k<<<(HDIM * HDIM / 4 + 255) / 256, 256, 0, stream>>>(kw, kwH, kwL, HDIM * HDIM / 4);
  split_k<<<(HDIM * HDIM / 4 + 255) / 256, 256, 0, stream>>>(vw, vwH, vwL, HDIM * HDIM / 4);
  split_k<<<(HDIM * HDIM / 4 + 255) / 256, 256, 0, stream>>>(ow, owH, owL, HDIM * HDIM / 4);

  const dim3 gg(MROWS / 128, HDIM / 128);
  gemm3p_k<0><<<gg, 256, 0, stream>>>(ftH, ftL, qwH, qwL, qb, QHp, QLp, nullptr);
  gemm3p_k<0><<<gg, 256, 0, stream>>>(ftH, ftL, kwH, kwL, kb, KHp, KLp, nullptr);
  gemm3p_k<1><<<gg, 256, 0, stream>>>(ftH, ftL, vwH, vwL, vb, VTp, nullptr, nullptr);

  attn3p_k<<<(SEQLEN / 64) * BATCH * NHEAD, 256, 0, stream>>>(QHp, QLp, KHp, KLp, VTp, atH, atL);

  gemm3p_k<2><<<gg, 256, 0, stream>>>(atH, atL, owH, owL, ob, nullptr, nullptr, proj);

  relu_ln_k<<<MROWS, 256, 0, stream>>>(proj, ln_g, ln_b, (float*)d_out);
}

// Round 3
// 539.615 us; speedup vs baseline: 4.0610x; 1.2139x over previous
//
#include <hip/hip_runtime.h>
#include <math.h>

#define HDIM 1024
#define NHEAD 16
#define HEADD 64
#define SEQLEN 2048
#define BATCH 4
#define MROWS (BATCH * SEQLEN)  // 8192
#define LN_EPS 1e-5f

typedef float f32x4 __attribute__((ext_vector_type(4)));
typedef short s16x8 __attribute__((ext_vector_type(8)));
typedef short s16x4 __attribute__((ext_vector_type(4)));
typedef __bf16 bf16x4 __attribute__((ext_vector_type(4)));

#define MFMA16(a, b, c) __builtin_amdgcn_mfma_f32_16x16x32_bf16((a), (b), (c), 0, 0, 0)

__device__ __forceinline__ void load_lds16(const __bf16* g, __bf16* l) {
  __builtin_amdgcn_global_load_lds((const __attribute__((address_space(1))) void*)g,
                                   (__attribute__((address_space(3))) void*)l, 16, 0, 0);
}

// ---------------------------------------------------------------------------
// fp32 -> bf16 (hi, lo) split, 4 elems/thread
// ---------------------------------------------------------------------------
__global__ __launch_bounds__(256) void split_k(const float* __restrict__ src,
                                               __bf16* __restrict__ h,
                                               __bf16* __restrict__ l, int n4) {
  int i = blockIdx.x * blockDim.x + threadIdx.x;
  if (i >= n4) return;
  float4 v = reinterpret_cast<const float4*>(src)[i];
  bf16x4 hv, lv;
  hv[0] = (__bf16)v.x; hv[1] = (__bf16)v.y; hv[2] = (__bf16)v.z; hv[3] = (__bf16)v.w;
  lv[0] = (__bf16)(v.x - (float)hv[0]);
  lv[1] = (__bf16)(v.y - (float)hv[1]);
  lv[2] = (__bf16)(v.z - (float)hv[2]);
  lv[3] = (__bf16)(v.w - (float)hv[3]);
  reinterpret_cast<bf16x4*>(h)[i] = hv;
  reinterpret_cast<bf16x4*>(l)[i] = lv;
}

// ---------------------------------------------------------------------------
// Split-bf16 3-pass MFMA GEMM: C = A @ W^T + bias.  (unchanged from round 2)
// ---------------------------------------------------------------------------
template <int EPI>
__global__ __launch_bounds__(256, 2) void gemm3p_k(
    const __bf16* __restrict__ AH, const __bf16* __restrict__ AL,
    const __bf16* __restrict__ BH, const __bf16* __restrict__ BL,
    const float* __restrict__ bias, __bf16* __restrict__ CH,
    __bf16* __restrict__ CL, float* __restrict__ CF) {
  __shared__ __bf16 smem[32768];

  const int tid = threadIdx.x;
  const int lane = tid & 63;
  const int w = tid >> 6;
  const int fr = lane & 15;
  const int g = lane >> 4;
  const int wm = w >> 1, wn = w & 1;
  const int m0 = blockIdx.x << 7;
  const int n0 = blockIdx.y << 7;

#define GSTAGE(buf, kt)                                                       \
  do {                                                                        \
    const int ke_ = (kt) * 32 + (lane & 3) * 8;                               \
    _Pragma("unroll") for (int c_ = 0; c_ < 2; ++c_) {                        \
      const int rr_ = 32 * w + 16 * c_ + (lane >> 2);                         \
      const int lo_ = (32 * w + 16 * c_) * 32;                                \
      load_lds16(AH + (size_t)(m0 + rr_) * HDIM + ke_, &smem[(buf)*4096 + lo_]); \
      load_lds16(AL + (size_t)(m0 + rr_) * HDIM + ke_, &smem[8192 + (buf)*4096 + lo_]); \
      load_lds16(BH + (size_t)(n0 + rr_) * HDIM + ke_, &smem[16384 + (buf)*4096 + lo_]); \
      load_lds16(BL + (size_t)(n0 + rr_) * HDIM + ke_, &smem[24576 + (buf)*4096 + lo_]); \
    }                                                                         \
  } while (0)

  f32x4 acc[4][4] = {};

  GSTAGE(0, 0);
  __syncthreads();

  for (int kt = 0; kt < HDIM / 32; ++kt) {
    const int buf = kt & 1;
    if (kt + 1 < HDIM / 32) GSTAGE(buf ^ 1, kt + 1);

    s16x8 aH[4], aL[4], bH[4], bL[4];
#pragma unroll
    for (int mi = 0; mi < 4; ++mi) {
      const int off = (wm * 64 + mi * 16 + fr) * 32 + g * 8;
      aH[mi] = *reinterpret_cast<const s16x8*>(&smem[buf * 4096 + off]);
      aL[mi] = *reinterpret_cast<const s16x8*>(&smem[8192 + buf * 4096 + off]);
    }
#pragma unroll
    for (int ni = 0; ni < 4; ++ni) {
      const int off = (wn * 64 + ni * 16 + fr) * 32 + g * 8;
      bH[ni] = *reinterpret_cast<const s16x8*>(&smem[16384 + buf * 4096 + off]);
      bL[ni] = *reinterpret_cast<const s16x8*>(&smem[24576 + buf * 4096 + off]);
    }
#pragma unroll
    for (int mi = 0; mi < 4; ++mi)
#pragma unroll
      for (int ni = 0; ni < 4; ++ni) {
        acc[mi][ni] = MFMA16(aH[mi], bH[ni], acc[mi][ni]);
        acc[mi][ni] = MFMA16(aH[mi], bL[ni], acc[mi][ni]);
        acc[mi][ni] = MFMA16(aL[mi], bH[ni], acc[mi][ni]);
      }
    __syncthreads();
  }

  float bv[4];
#pragma unroll
  for (int ni = 0; ni < 4; ++ni) bv[ni] = bias[n0 + wn * 64 + ni * 16 + fr];

  if (EPI == 0) {  // head layout [B,NH,S,HD], bf16 hi/lo
#pragma unroll
    for (int mi = 0; mi < 4; ++mi)
#pragma unroll
      for (int ni = 0; ni < 4; ++ni)
#pragma unroll
        for (int r = 0; r < 4; ++r) {
          const float v = acc[mi][ni][r] + bv[ni];
          const int m = m0 + wm * 64 + mi * 16 + 4 * g + r;
          const int n = n0 + wn * 64 + ni * 16 + fr;
          const int b = m >> 11, s = m & 2047, h = n >> 6, d = n & 63;
          const size_t o = ((size_t)(b * NHEAD + h) * SEQLEN + s) * HEADD + d;
          const __bf16 hb = (__bf16)v;
          CH[o] = hb;
          CL[o] = (__bf16)(v - (float)hb);
        }
  } else if (EPI == 2) {  // plain fp32 [M][H]
#pragma unroll
    for (int mi = 0; mi < 4; ++mi)
#pragma unroll
      for (int ni = 0; ni < 4; ++ni)
#pragma unroll
        for (int r = 0; r < 4; ++r) {
          const int m = m0 + wm * 64 + mi * 16 + 4 * g + r;
          const int n = n0 + wn * 64 + ni * 16 + fr;
          CF[(size_t)m * HDIM + n] = acc[mi][ni][r] + bv[ni];
        }
  } else {  // EPI == 1: transposed Vt [B,NH,HD,S] bf16 hi via LDS transpose
    __syncthreads();
#pragma unroll
    for (int mi = 0; mi < 4; ++mi)
#pragma unroll
      for (int ni = 0; ni < 4; ++ni)
#pragma unroll
        for (int r = 0; r < 4; ++r) {
          const float v = acc[mi][ni][r] + bv[ni];
          const int nl = wn * 64 + ni * 16 + fr;
          const int ml = wm * 64 + mi * 16 + 4 * g + r;
          smem[nl * 128 + (((ml >> 3) ^ (nl & 7)) << 3) + (ml & 7)] = (__bf16)v;
        }
    __syncthreads();
    const int nl = tid >> 1, mh = tid & 1;
    const int b = m0 >> 11, s0 = m0 & 2047;
    const int gn = n0 + nl, h = gn >> 6, d = gn & 63;
#pragma unroll
    for (int j = 0; j < 8; ++j) {
      const int cm = mh * 8 + j;
      s16x8 vv = *reinterpret_cast<const s16x8*>(&smem[nl * 128 + ((cm ^ (nl & 7)) << 3)]);
      const size_t o = ((size_t)((b * NHEAD + h) * HEADD + d)) * SEQLEN + s0 + cm * 8;
      *reinterpret_cast<s16x8*>(&CH[o]) = vv;
    }
  }
#undef GSTAGE
}

// ---------------------------------------------------------------------------
// Flash attention v2: swapped QK^T (D = S^T[key][q]), lane-local softmax,
// QBLK=128 (4 waves x 2 q-blocks of 16), KVBLK=64, defer-max, setprio.
// K hi/lo + Vt double-buffered via pre-swizzled global_load_lds; P hi/lo
// round-trips LDS as packed b64 writes / b128 reads (within-wave, no barrier).
// LDS: KH 16K | KL 16K | V 16K (all dbuf) | PH 16K | PL 16K = 80 KB.
// ---------------------------------------------------------------------------
__global__ __launch_bounds__(256, 2) void attn4_k(
    const __bf16* __restrict__ QH, const __bf16* __restrict__ QL,
    const __bf16* __restrict__ KH, const __bf16* __restrict__ KL,
    const __bf16* __restrict__ VT, __bf16* __restrict__ OH,
    __bf16* __restrict__ OL) {
  __shared__ __bf16 smem[40960];  // 80 KB

  const int tid = threadIdx.x;
  const int lane = tid & 63;
  const int w = tid >> 6;
  const int fr = lane & 15;
  const int g = lane >> 4;
  const int f7 = fr & 7;

  // XCD swizzle: concurrent blocks on one XCD share few bh (KV L2 locality)
  const int blk = blockIdx.x;
  const int xcd = blk & 7, idx = blk >> 3;     // grid = 1024
  const int bh = xcd * 8 + (idx >> 4);         // 64 bh
  const int qt = idx & 15;                     // 16 q-tiles of 128
  const int q0 = qt << 7;
  const size_t bhO = (size_t)bh * SEQLEN * HEADD;

  // Q fragments (B-operand): row=fr <-> q = q0 + w*32 + qb*16 + fr, k=ks*32+g*8+i
  s16x8 qHf[2][2], qLf[2][2];
#pragma unroll
  for (int qb = 0; qb < 2; ++qb) {
    const size_t qoff = bhO + (size_t)(q0 + w * 32 + qb * 16 + fr) * HEADD;
#pragma unroll
    for (int ks = 0; ks < 2; ++ks) {
      qHf[qb][ks] = *reinterpret_cast<const s16x8*>(&QH[qoff + ks * 32 + g * 8]);
      qLf[qb][ks] = *reinterpret_cast<const s16x8*>(&QL[qoff + ks * 32 + g * 8]);
    }
  }

#define ASTAGE(buf, kt)                                                        \
  do {                                                                         \
    const int kv0_ = (kt) * 64;                                                \
    const int rsub_ = lane >> 3;                                               \
    const int ch_ = (lane & 7) ^ rsub_;                                        \
    _Pragma("unroll") for (int i_ = 0; i_ < 6; ++i_) {                         \
      const int L_ = w * 6 + i_;                                               \
      const int t_ = L_ >> 3, sub_ = L_ & 7;                                   \
      __bf16* lp_ = &smem[t_ * 8192 + (buf)*4096 + sub_ * 512];                \
      if (t_ < 2) {                                                            \
        const __bf16* base_ = (t_ == 0) ? KH : KL;                             \
        load_lds16(base_ + bhO + (size_t)(kv0_ + sub_ * 8 + rsub_) * HEADD + ch_ * 8, lp_); \
      } else {                                                                 \
        load_lds16(VT + ((size_t)bh * HEADD + sub_ * 8 + rsub_) * SEQLEN + kv0_ + ch_ * 8, lp_); \
      }                                                                        \
    }                                                                          \
  } while (0)

  f32x4 oacc[2][4] = {};
  float m_run[2] = {-1e30f, -1e30f};
  float l_run[2] = {0.f, 0.f};

  ASTAGE(0, 0);
  __syncthreads();

  for (int kt = 0; kt < SEQLEN / 64; ++kt) {
    const int buf = kt & 1;
    if (kt + 1 < SEQLEN / 64) ASTAGE(buf ^ 1, kt + 1);

    // ---- S^T = K Q^T (3-pass split): sf[qb][kb][r] = S[key=kb*16+4g+r][q] ----
    f32x4 sf[2][4] = {};
    __builtin_amdgcn_s_setprio(1);
#pragma unroll
    for (int kb = 0; kb < 4; ++kb) {
      s16x8 kh[2], kl[2];
#pragma unroll
      for (int ks = 0; ks < 2; ++ks) {
        const int off = (kb * 16 + fr) * 64 + (((ks * 4 + g) ^ f7) << 3);
        kh[ks] = *reinterpret_cast<const s16x8*>(&smem[buf * 4096 + off]);
        kl[ks] = *reinterpret_cast<const s16x8*>(&smem[8192 + buf * 4096 + off]);
      }
#pragma unroll
      for (int qb = 0; qb < 2; ++qb)
#pragma unroll
        for (int ks = 0; ks < 2; ++ks) {
          sf[qb][kb] = MFMA16(kh[ks], qHf[qb][ks], sf[qb][kb]);
          sf[qb][kb] = MFMA16(kl[ks], qHf[qb][ks], sf[qb][kb]);
          sf[qb][kb] = MFMA16(kh[ks], qLf[qb][ks], sf[qb][kb]);
        }
    }
    __builtin_amdgcn_s_setprio(0);

    // ---- online softmax, lane-local (lane owns q = ...+fr, 16 keys) ----
    float mxa[2];
#pragma unroll
    for (int qb = 0; qb < 2; ++qb) {
      float mx = -1e30f;
#pragma unroll
      for (int kb = 0; kb < 4; ++kb) {
        sf[qb][kb] *= 2.0f;  // / TEMP(0.5)
#pragma unroll
        for (int r = 0; r < 4; ++r) mx = fmaxf(mx, sf[qb][kb][r]);
      }
      mx = fmaxf(mx, __shfl_xor(mx, 16));
      mx = fmaxf(mx, __shfl_xor(mx, 32));
      mxa[qb] = mx;
    }
    const bool ok = (mxa[0] <= m_run[0] + 8.f) && (mxa[1] <= m_run[1] + 8.f);
    if (!__all(ok)) {  // rescale path (rare after warm-up)
#pragma unroll
      for (int qb = 0; qb < 2; ++qb) {
        const float mn = fmaxf(m_run[qb], mxa[qb]);
        const float corr = __expf(m_run[qb] - mn);
        m_run[qb] = mn;
        l_run[qb] *= corr;
        float cr[4];
#pragma unroll
        for (int r = 0; r < 4; ++r) cr[r] = __shfl(corr, 4 * g + r);
#pragma unroll
        for (int di = 0; di < 4; ++di)
#pragma unroll
          for (int r = 0; r < 4; ++r) oacc[qb][di][r] *= cr[r];
      }
    }
#pragma unroll
    for (int qb = 0; qb < 2; ++qb) {
      float ps = 0.f;
#pragma unroll
      for (int kb = 0; kb < 4; ++kb)
#pragma unroll
        for (int r = 0; r < 4; ++r) {
          const float p = __expf(sf[qb][kb][r] - m_run[qb]);
          sf[qb][kb][r] = p;
          ps += p;
        }
      ps += __shfl_xor(ps, 16);
      ps += __shfl_xor(ps, 32);
      l_run[qb] += ps;
    }

    // ---- P (hi/lo) -> LDS as packed b64 (4 consecutive keys per lane) ----
#pragma unroll
    for (int qb = 0; qb < 2; ++qb) {
      const int q = w * 32 + qb * 16 + fr;
#pragma unroll
      for (int kb = 0; kb < 4; ++kb) {
        s16x4 hh, ll;
#pragma unroll
        for (int r = 0; r < 4; ++r) {
          const float p = sf[qb][kb][r];
          const __bf16 hb = (__bf16)p;
          hh[r] = __builtin_bit_cast(short, hb);
          ll[r] = __builtin_bit_cast(short, (__bf16)(p - (float)hb));
        }
        const int cd = 2 * kb + (g >> 1);
        const int off = q * 64 + ((cd ^ f7) << 3) + (g & 1) * 4;
        *reinterpret_cast<s16x4*>(&smem[24576 + off]) = hh;
        *reinterpret_cast<s16x4*>(&smem[32768 + off]) = ll;
      }
    }

    // ---- O += P @ V (2-pass: Ph*V + Pl*V), within-wave P readback ----
    __builtin_amdgcn_s_setprio(1);
#pragma unroll
    for (int ks = 0; ks < 2; ++ks) {
      s16x8 pH[2], pL[2];
#pragma unroll
      for (int qb = 0; qb < 2; ++qb) {
        const int q = w * 32 + qb * 16 + fr;
        const int off = q * 64 + (((ks * 4 + g) ^ f7) << 3);
        pH[qb] = *reinterpret_cast<const s16x8*>(&smem[24576 + off]);
        pL[qb] = *reinterpret_cast<const s16x8*>(&smem[32768 + off]);
      }
#pragma unroll
      for (int di = 0; di < 4; ++di) {
        const int d = di * 16 + fr;
        const int voff = d * 64 + (((ks * 4 + g) ^ f7) << 3);
        s16x8 vf = *reinterpret_cast<const s16x8*>(&smem[16384 + buf * 4096 + voff]);
#pragma unroll
        for (int qb = 0; qb < 2; ++qb) {
          oacc[qb][di] = MFMA16(pH[qb], vf, oacc[qb][di]);
          oacc[qb][di] = MFMA16(pL[qb], vf, oacc[qb][di]);
        }
      }
    }
    __builtin_amdgcn_s_setprio(0);
    __syncthreads();
  }

  // ---- epilogue: normalize (l lives in fr-domain -> shfl to 4g+r), write ----
  const int b = bh >> 4, h = bh & 15;
#pragma unroll
  for (int qb = 0; qb < 2; ++qb) {
    const float inv = 1.0f / l_run[qb];
    float iv[4];
#pragma unroll
    for (int r = 0; r < 4; ++r) iv[r] = __shfl(inv, 4 * g + r);
#pragma unroll
    for (int di = 0; di < 4; ++di)
#pragma unroll
      for (int r = 0; r < 4; ++r) {
        const float v = oacc[qb][di][r] * iv[r];
        const int srow = q0 + w * 32 + qb * 16 + 4 * g + r;
        const size_t o = ((size_t)b * SEQLEN + srow) * HDIM + h * 64 + di * 16 + fr;
        const __bf16 hb = (__bf16)v;
        OH[o] = hb;
        OL[o] = (__bf16)(v - (float)hb);
      }
  }
#undef ASTAGE
}

// ---------------------------------------------------------------------------
// Fused ReLU + LayerNorm over rows of 1024. One block (256 thr) per row.
// ---------------------------------------------------------------------------
__global__ __launch_bounds__(256) void relu_ln_k(const float* __restrict__ X,
                                                 const float* __restrict__ gam,
                                                 const float* __restrict__ bta,
                                                 float* __restrict__ out) {
  __shared__ float red[8];
  const int row = blockIdx.x;
  const int tid = threadIdx.x;
  const int c = tid << 2;

  const float4 v = *reinterpret_cast<const float4*>(&X[(size_t)row * HDIM + c]);
  float x[4] = {fmaxf(v.x, 0.f), fmaxf(v.y, 0.f), fmaxf(v.z, 0.f), fmaxf(v.w, 0.f)};
  float sum = x[0] + x[1] + x[2] + x[3];
  float ss = x[0] * x[0] + x[1] * x[1] + x[2] * x[2] + x[3] * x[3];
#pragma unroll
  for (int off = 1; off < 64; off <<= 1) {
    sum += __shfl_xor(sum, off);
    ss += __shfl_xor(ss, off);
  }
  const int wid = tid >> 6;
  if ((tid & 63) == 0) {
    red[wid] = sum;
    red[4 + wid] = ss;
  }
  __syncthreads();
  sum = red[0] + red[1] + red[2] + red[3];
  ss = red[4] + red[5] + red[6] + red[7];
  const float mean = sum * (1.0f / HDIM);
  const float var = ss * (1.0f / HDIM) - mean * mean;
  const float rstd = rsqrtf(var + LN_EPS);

  const float4 gv = *reinterpret_cast<const float4*>(&gam[c]);
  const float4 bv = *reinterpret_cast<const float4*>(&bta[c]);
  float4 o;
  o.x = (x[0] - mean) * rstd * gv.x + bv.x;
  o.y = (x[1] - mean) * rstd * gv.y + bv.y;
  o.z = (x[2] - mean) * rstd * gv.z + bv.z;
  o.w = (x[3] - mean) * rstd * gv.w + bv.w;
  *reinterpret_cast<float4*>(&out[(size_t)row * HDIM + c]) = o;
}

// ---------------------------------------------------------------------------
// Launch. ws (128 MB):
//  [0,16M): wts hi (qw,kw,vw,ow @2MB) + wts lo (@2MB each)
//  [16,48M): QH,QL        -> later proj fp32 (32MB)
//  [48,80M): KH,KL
//  [80,96M): VtH
//  [96,128M): featH,featL -> later attnH,attnL
// ---------------------------------------------------------------------------
extern "C" void kernel_launch(void* const* d_in, const int* in_sizes, int n_in,
                              void* d_out, int out_size, void* d_ws, size_t ws_size,
                              hipStream_t stream) {
  const float* feat = (const float*)d_in[0];
  const float* qw = (const float*)d_in[1];
  const float* qb = (const float*)d_in[2];
  const float* kw = (const float*)d_in[3];
  const float* kb = (const float*)d_in[4];
  const float* vw = (const float*)d_in[5];
  const float* vb = (const float*)d_in[6];
  const float* ow = (const float*)d_in[7];
  const float* ob = (const float*)d_in[8];
  const float* ln_g = (const float*)d_in[9];
  const float* ln_b = (const float*)d_in[10];

  char* ws = (char*)d_ws;
  const size_t MB = 1u << 20;
  __bf16* qwH = (__bf16*)(ws + 0 * MB);
  __bf16* kwH = (__bf16*)(ws + 2 * MB);
  __bf16* vwH = (__bf16*)(ws + 4 * MB);
  __bf16* owH = (__bf16*)(ws + 6 * MB);
  __bf16* qwL = (__bf16*)(ws + 8 * MB);
  __bf16* kwL = (__bf16*)(ws + 10 * MB);
  __bf16* vwL = (__bf16*)(ws + 12 * MB);
  __bf16* owL = (__bf16*)(ws + 14 * MB);
  __bf16* QHp = (__bf16*)(ws + 16 * MB);
  __bf16* QLp = (__bf16*)(ws + 32 * MB);
  __bf16* KHp = (__bf16*)(ws + 48 * MB);
  __bf16* KLp = (__bf16*)(ws + 64 * MB);
  __bf16* VTp = (__bf16*)(ws + 80 * MB);
  __bf16* ftH = (__bf16*)(ws + 96 * MB);
  __bf16* ftL = (__bf16*)(ws + 112 * MB);
  __bf16* atH = ftH;  // reuse after feat dead
  __bf16* atL = ftL;
  float* proj = (float*)(ws + 16 * MB);  // reuse Q region after attention

  // splits
  split_k<<<(MROWS * HDIM / 4 + 255) / 256, 256, 0, stream>>>(feat, ftH, ftL, MROWS * HDIM / 4);
  split_k<<<(HDIM * HDIM / 4 + 255) / 256, 256, 0, stream>>>(qw, qwH, qwL, HDIM * HDIM / 4);
  split_k<<<(HDIM * HDIM / 4 + 255) / 256, 256, 0, stream>>>(kw, kwH, kwL, HDIM * HDIM / 4);
  split_k<<<(HDIM * HDIM / 4 + 255) / 256, 256, 0, stream>>>(vw, vwH, vwL, HDIM * HDIM / 4);
  split_k<<<(HDIM * HDIM / 4 + 255) / 256, 256, 0, stream>>>(ow, owH, owL, HDIM * HDIM / 4);

  const dim3 gg(MROWS / 128, HDIM / 128);
  gemm3p_k<0><<<gg, 256, 0, stream>>>(ftH, ftL, qwH, qwL, qb, QHp, QLp, nullptr);
  gemm3p_k<0><<<gg, 256, 0, stream>>>(ftH, ftL, kwH, kwL, kb, KHp, KLp, nullptr);
  gemm3p_k<1><<<gg, 256, 0, stream>>>(ftH, ftL, vwH, vwL, vb, VTp, nullptr, nullptr);

  attn4_k<<<BATCH * NHEAD * (SEQLEN / 128), 256, 0, stream>>>(QHp, QLp, KHp, KLp, VTp, atH, atL);

  gemm3p_k<2><<<gg, 256, 0, stream>>>(atH, atL, owH, owL, ob, nullptr, nullptr, proj);

  relu_ln_k<<<MROWS, 256, 0, stream>>>(proj, ln_g, ln_b, (float*)d_out);
}

// Round 4
// 457.206 us; speedup vs baseline: 4.7930x; 1.1802x over previous
//
#include <hip/hip_runtime.h>
#include <math.h>

#define HDIM 1024
#define NHEAD 16
#define HEADD 64
#define SEQLEN 2048
#define BATCH 4
#define MROWS (BATCH * SEQLEN)  // 8192
#define LN_EPS 1e-5f

typedef float f32x4 __attribute__((ext_vector_type(4)));
typedef short s16x8 __attribute__((ext_vector_type(8)));
typedef short s16x4 __attribute__((ext_vector_type(4)));
typedef __bf16 bf16x4 __attribute__((ext_vector_type(4)));

#define MFMA16(a, b, c) __builtin_amdgcn_mfma_f32_16x16x32_bf16((a), (b), (c), 0, 0, 0)

__device__ __forceinline__ void load_lds16(const __bf16* g, __bf16* l) {
  __builtin_amdgcn_global_load_lds((const __attribute__((address_space(1))) void*)g,
                                   (__attribute__((address_space(3))) void*)l, 16, 0, 0);
}

// ---------------------------------------------------------------------------
// fp32 -> bf16 (hi, lo) split, 4 elems/thread
// ---------------------------------------------------------------------------
__global__ __launch_bounds__(256) void split_k(const float* __restrict__ src,
                                               __bf16* __restrict__ h,
                                               __bf16* __restrict__ l, int n4) {
  int i = blockIdx.x * blockDim.x + threadIdx.x;
  if (i >= n4) return;
  float4 v = reinterpret_cast<const float4*>(src)[i];
  bf16x4 hv, lv;
  hv[0] = (__bf16)v.x; hv[1] = (__bf16)v.y; hv[2] = (__bf16)v.z; hv[3] = (__bf16)v.w;
  lv[0] = (__bf16)(v.x - (float)hv[0]);
  lv[1] = (__bf16)(v.y - (float)hv[1]);
  lv[2] = (__bf16)(v.z - (float)hv[2]);
  lv[3] = (__bf16)(v.w - (float)hv[3]);
  reinterpret_cast<bf16x4*>(h)[i] = hv;
  reinterpret_cast<bf16x4*>(l)[i] = lv;
}

// ---------------------------------------------------------------------------
// Split-bf16 MFMA GEMM: C = A @ W^T + bias.
// PASSES==3: AhBh + AhBl + AlBh (Q,K proj — exp-sensitive).
// PASSES==2: AhBh + AlBh (full-prec activations x bf16 weights; V/out proj).
// 128x128 tile, BK=32, 4 waves, 16x16x32 MFMA, global_load_lds staging.
// EPI: 0 = head-layout bf16 hi/lo ; 1 = transposed Vt bf16 hi ; 2 = fp32.
// ---------------------------------------------------------------------------
template <int EPI, int PASSES>
__global__ __launch_bounds__(256, 2) void gemm3p_k(
    const __bf16* __restrict__ AH, const __bf16* __restrict__ AL,
    const __bf16* __restrict__ BH, const __bf16* __restrict__ BL,
    const float* __restrict__ bias, __bf16* __restrict__ CH,
    __bf16* __restrict__ CL, float* __restrict__ CF) {
  __shared__ __bf16 smem[32768];

  const int tid = threadIdx.x;
  const int lane = tid & 63;
  const int w = tid >> 6;
  const int fr = lane & 15;
  const int g = lane >> 4;
  const int wm = w >> 1, wn = w & 1;
  const int m0 = blockIdx.x << 7;
  const int n0 = blockIdx.y << 7;

#define GSTAGE(buf, kt)                                                       \
  do {                                                                        \
    const int ke_ = (kt) * 32 + (lane & 3) * 8;                               \
    _Pragma("unroll") for (int c_ = 0; c_ < 2; ++c_) {                        \
      const int rr_ = 32 * w + 16 * c_ + (lane >> 2);                         \
      const int lo_ = (32 * w + 16 * c_) * 32;                                \
      load_lds16(AH + (size_t)(m0 + rr_) * HDIM + ke_, &smem[(buf)*4096 + lo_]); \
      load_lds16(AL + (size_t)(m0 + rr_) * HDIM + ke_, &smem[8192 + (buf)*4096 + lo_]); \
      load_lds16(BH + (size_t)(n0 + rr_) * HDIM + ke_, &smem[16384 + (buf)*4096 + lo_]); \
      if (PASSES == 3)                                                        \
        load_lds16(BL + (size_t)(n0 + rr_) * HDIM + ke_, &smem[24576 + (buf)*4096 + lo_]); \
    }                                                                         \
  } while (0)

  f32x4 acc[4][4] = {};

  GSTAGE(0, 0);
  __syncthreads();

  for (int kt = 0; kt < HDIM / 32; ++kt) {
    const int buf = kt & 1;
    if (kt + 1 < HDIM / 32) GSTAGE(buf ^ 1, kt + 1);

    s16x8 aH[4], aL[4], bH[4], bL[4];
#pragma unroll
    for (int mi = 0; mi < 4; ++mi) {
      const int off = (wm * 64 + mi * 16 + fr) * 32 + g * 8;
      aH[mi] = *reinterpret_cast<const s16x8*>(&smem[buf * 4096 + off]);
      aL[mi] = *reinterpret_cast<const s16x8*>(&smem[8192 + buf * 4096 + off]);
    }
#pragma unroll
    for (int ni = 0; ni < 4; ++ni) {
      const int off = (wn * 64 + ni * 16 + fr) * 32 + g * 8;
      bH[ni] = *reinterpret_cast<const s16x8*>(&smem[16384 + buf * 4096 + off]);
      if (PASSES == 3)
        bL[ni] = *reinterpret_cast<const s16x8*>(&smem[24576 + buf * 4096 + off]);
    }
#pragma unroll
    for (int mi = 0; mi < 4; ++mi)
#pragma unroll
      for (int ni = 0; ni < 4; ++ni) {
        acc[mi][ni] = MFMA16(aH[mi], bH[ni], acc[mi][ni]);
        if (PASSES == 3) acc[mi][ni] = MFMA16(aH[mi], bL[ni], acc[mi][ni]);
        acc[mi][ni] = MFMA16(aL[mi], bH[ni], acc[mi][ni]);
      }
    __syncthreads();
  }

  float bv[4];
#pragma unroll
  for (int ni = 0; ni < 4; ++ni) bv[ni] = bias[n0 + wn * 64 + ni * 16 + fr];

  if (EPI == 0) {  // head layout [B,NH,S,HD], bf16 hi/lo
#pragma unroll
    for (int mi = 0; mi < 4; ++mi)
#pragma unroll
      for (int ni = 0; ni < 4; ++ni)
#pragma unroll
        for (int r = 0; r < 4; ++r) {
          const float v = acc[mi][ni][r] + bv[ni];
          const int m = m0 + wm * 64 + mi * 16 + 4 * g + r;
          const int n = n0 + wn * 64 + ni * 16 + fr;
          const int b = m >> 11, s = m & 2047, h = n >> 6, d = n & 63;
          const size_t o = ((size_t)(b * NHEAD + h) * SEQLEN + s) * HEADD + d;
          const __bf16 hb = (__bf16)v;
          CH[o] = hb;
          CL[o] = (__bf16)(v - (float)hb);
        }
  } else if (EPI == 2) {  // plain fp32 [M][H]
#pragma unroll
    for (int mi = 0; mi < 4; ++mi)
#pragma unroll
      for (int ni = 0; ni < 4; ++ni)
#pragma unroll
        for (int r = 0; r < 4; ++r) {
          const int m = m0 + wm * 64 + mi * 16 + 4 * g + r;
          const int n = n0 + wn * 64 + ni * 16 + fr;
          CF[(size_t)m * HDIM + n] = acc[mi][ni][r] + bv[ni];
        }
  } else {  // EPI == 1: transposed Vt [B,NH,HD,S] bf16 hi via LDS transpose
    __syncthreads();
#pragma unroll
    for (int mi = 0; mi < 4; ++mi)
#pragma unroll
      for (int ni = 0; ni < 4; ++ni)
#pragma unroll
        for (int r = 0; r < 4; ++r) {
          const float v = acc[mi][ni][r] + bv[ni];
          const int nl = wn * 64 + ni * 16 + fr;
          const int ml = wm * 64 + mi * 16 + 4 * g + r;
          smem[nl * 128 + (((ml >> 3) ^ (nl & 7)) << 3) + (ml & 7)] = (__bf16)v;
        }
    __syncthreads();
    const int nl = tid >> 1, mh = tid & 1;
    const int b = m0 >> 11, s0 = m0 & 2047;
    const int gn = n0 + nl, h = gn >> 6, d = gn & 63;
#pragma unroll
    for (int j = 0; j < 8; ++j) {
      const int cm = mh * 8 + j;
      s16x8 vv = *reinterpret_cast<const s16x8*>(&smem[nl * 128 + ((cm ^ (nl & 7)) << 3)]);
      const size_t o = ((size_t)((b * NHEAD + h) * HEADD + d)) * SEQLEN + s0 + cm * 8;
      *reinterpret_cast<s16x8*>(&CH[o]) = vv;
    }
  }
#undef GSTAGE
}

// ---------------------------------------------------------------------------
// Flash attention v3: swapped QK^T (3-pass split), lane-local softmax,
// QBLK=128 (4 waves x 2 q-blocks), KVBLK=64, defer-max, setprio,
// SINGLE-pass PV (P hi only).
// LDS: KH 16K | KL 16K | V 16K (dbuf) | PH 16K = 64 KB.
// ---------------------------------------------------------------------------
__global__ __launch_bounds__(256, 2) void attn5_k(
    const __bf16* __restrict__ QH, const __bf16* __restrict__ QL,
    const __bf16* __restrict__ KH, const __bf16* __restrict__ KL,
    const __bf16* __restrict__ VT, __bf16* __restrict__ OH,
    __bf16* __restrict__ OL) {
  __shared__ __bf16 smem[32768];  // 64 KB

  const int tid = threadIdx.x;
  const int lane = tid & 63;
  const int w = tid >> 6;
  const int fr = lane & 15;
  const int g = lane >> 4;
  const int f7 = fr & 7;

  // XCD swizzle: concurrent blocks on one XCD share few bh (KV L2 locality)
  const int blk = blockIdx.x;
  const int xcd = blk & 7, idx = blk >> 3;     // grid = 1024
  const int bh = xcd * 8 + (idx >> 4);         // 64 bh
  const int qt = idx & 15;                     // 16 q-tiles of 128
  const int q0 = qt << 7;
  const size_t bhO = (size_t)bh * SEQLEN * HEADD;

  // Q fragments (B-operand): row=fr <-> q = q0 + w*32 + qb*16 + fr, k=ks*32+g*8+i
  s16x8 qHf[2][2], qLf[2][2];
#pragma unroll
  for (int qb = 0; qb < 2; ++qb) {
    const size_t qoff = bhO + (size_t)(q0 + w * 32 + qb * 16 + fr) * HEADD;
#pragma unroll
    for (int ks = 0; ks < 2; ++ks) {
      qHf[qb][ks] = *reinterpret_cast<const s16x8*>(&QH[qoff + ks * 32 + g * 8]);
      qLf[qb][ks] = *reinterpret_cast<const s16x8*>(&QL[qoff + ks * 32 + g * 8]);
    }
  }

#define ASTAGE(buf, kt)                                                        \
  do {                                                                         \
    const int kv0_ = (kt) * 64;                                                \
    const int rsub_ = lane >> 3;                                               \
    const int ch_ = (lane & 7) ^ rsub_;                                        \
    _Pragma("unroll") for (int i_ = 0; i_ < 6; ++i_) {                         \
      const int L_ = w * 6 + i_;                                               \
      const int t_ = L_ >> 3, sub_ = L_ & 7;                                   \
      __bf16* lp_ = &smem[t_ * 8192 + (buf)*4096 + sub_ * 512];                \
      if (t_ < 2) {                                                            \
        const __bf16* base_ = (t_ == 0) ? KH : KL;                             \
        load_lds16(base_ + bhO + (size_t)(kv0_ + sub_ * 8 + rsub_) * HEADD + ch_ * 8, lp_); \
      } else {                                                                 \
        load_lds16(VT + ((size_t)bh * HEADD + sub_ * 8 + rsub_) * SEQLEN + kv0_ + ch_ * 8, lp_); \
      }                                                                        \
    }                                                                          \
  } while (0)

  f32x4 oacc[2][4] = {};
  float m_run[2] = {-1e30f, -1e30f};
  float l_run[2] = {0.f, 0.f};

  ASTAGE(0, 0);
  __syncthreads();

  for (int kt = 0; kt < SEQLEN / 64; ++kt) {
    const int buf = kt & 1;
    if (kt + 1 < SEQLEN / 64) ASTAGE(buf ^ 1, kt + 1);

    // ---- S^T = K Q^T (3-pass split): sf[qb][kb][r] = S[key=kb*16+4g+r][q] ----
    f32x4 sf[2][4] = {};
    __builtin_amdgcn_s_setprio(1);
#pragma unroll
    for (int kb = 0; kb < 4; ++kb) {
      s16x8 kh[2], kl[2];
#pragma unroll
      for (int ks = 0; ks < 2; ++ks) {
        const int off = (kb * 16 + fr) * 64 + (((ks * 4 + g) ^ f7) << 3);
        kh[ks] = *reinterpret_cast<const s16x8*>(&smem[buf * 4096 + off]);
        kl[ks] = *reinterpret_cast<const s16x8*>(&smem[8192 + buf * 4096 + off]);
      }
#pragma unroll
      for (int qb = 0; qb < 2; ++qb)
#pragma unroll
        for (int ks = 0; ks < 2; ++ks) {
          sf[qb][kb] = MFMA16(kh[ks], qHf[qb][ks], sf[qb][kb]);
          sf[qb][kb] = MFMA16(kl[ks], qHf[qb][ks], sf[qb][kb]);
          sf[qb][kb] = MFMA16(kh[ks], qLf[qb][ks], sf[qb][kb]);
        }
    }
    __builtin_amdgcn_s_setprio(0);

    // ---- online softmax, lane-local (lane owns q = ...+fr, 16 keys) ----
    float mxa[2];
#pragma unroll
    for (int qb = 0; qb < 2; ++qb) {
      float mx = -1e30f;
#pragma unroll
      for (int kb = 0; kb < 4; ++kb) {
        sf[qb][kb] *= 2.0f;  // / TEMP(0.5)
#pragma unroll
        for (int r = 0; r < 4; ++r) mx = fmaxf(mx, sf[qb][kb][r]);
      }
      mx = fmaxf(mx, __shfl_xor(mx, 16));
      mx = fmaxf(mx, __shfl_xor(mx, 32));
      mxa[qb] = mx;
    }
    const bool ok = (mxa[0] <= m_run[0] + 8.f) && (mxa[1] <= m_run[1] + 8.f);
    if (!__all(ok)) {  // rescale path (rare after warm-up)
#pragma unroll
      for (int qb = 0; qb < 2; ++qb) {
        const float mn = fmaxf(m_run[qb], mxa[qb]);
        const float corr = __expf(m_run[qb] - mn);
        m_run[qb] = mn;
        l_run[qb] *= corr;
        float cr[4];
#pragma unroll
        for (int r = 0; r < 4; ++r) cr[r] = __shfl(corr, 4 * g + r);
#pragma unroll
        for (int di = 0; di < 4; ++di)
#pragma unroll
          for (int r = 0; r < 4; ++r) oacc[qb][di][r] *= cr[r];
      }
    }
#pragma unroll
    for (int qb = 0; qb < 2; ++qb) {
      float ps = 0.f;
#pragma unroll
      for (int kb = 0; kb < 4; ++kb)
#pragma unroll
        for (int r = 0; r < 4; ++r) {
          const float p = __expf(sf[qb][kb][r] - m_run[qb]);
          sf[qb][kb][r] = p;
          ps += p;
        }
      ps += __shfl_xor(ps, 16);
      ps += __shfl_xor(ps, 32);
      l_run[qb] += ps;
    }

    // ---- P (hi only) -> LDS as packed b64 (4 consecutive keys per lane) ----
#pragma unroll
    for (int qb = 0; qb < 2; ++qb) {
      const int q = w * 32 + qb * 16 + fr;
#pragma unroll
      for (int kb = 0; kb < 4; ++kb) {
        s16x4 hh;
#pragma unroll
        for (int r = 0; r < 4; ++r)
          hh[r] = __builtin_bit_cast(short, (__bf16)sf[qb][kb][r]);
        const int cd = 2 * kb + (g >> 1);
        const int off = q * 64 + ((cd ^ f7) << 3) + (g & 1) * 4;
        *reinterpret_cast<s16x4*>(&smem[24576 + off]) = hh;
      }
    }

    // ---- O += P @ V (single pass), within-wave P readback ----
    __builtin_amdgcn_s_setprio(1);
#pragma unroll
    for (int ks = 0; ks < 2; ++ks) {
      s16x8 pH[2];
#pragma unroll
      for (int qb = 0; qb < 2; ++qb) {
        const int q = w * 32 + qb * 16 + fr;
        const int off = q * 64 + (((ks * 4 + g) ^ f7) << 3);
        pH[qb] = *reinterpret_cast<const s16x8*>(&smem[24576 + off]);
      }
#pragma unroll
      for (int di = 0; di < 4; ++di) {
        const int d = di * 16 + fr;
        const int voff = d * 64 + (((ks * 4 + g) ^ f7) << 3);
        s16x8 vf = *reinterpret_cast<const s16x8*>(&smem[16384 + buf * 4096 + voff]);
#pragma unroll
        for (int qb = 0; qb < 2; ++qb)
          oacc[qb][di] = MFMA16(pH[qb], vf, oacc[qb][di]);
      }
    }
    __builtin_amdgcn_s_setprio(0);
    __syncthreads();
  }

  // ---- epilogue: normalize (l lives in fr-domain -> shfl to 4g+r), write ----
  const int b = bh >> 4, h = bh & 15;
#pragma unroll
  for (int qb = 0; qb < 2; ++qb) {
    const float inv = 1.0f / l_run[qb];
    float iv[4];
#pragma unroll
    for (int r = 0; r < 4; ++r) iv[r] = __shfl(inv, 4 * g + r);
#pragma unroll
    for (int di = 0; di < 4; ++di)
#pragma unroll
      for (int r = 0; r < 4; ++r) {
        const float v = oacc[qb][di][r] * iv[r];
        const int srow = q0 + w * 32 + qb * 16 + 4 * g + r;
        const size_t o = ((size_t)b * SEQLEN + srow) * HDIM + h * 64 + di * 16 + fr;
        const __bf16 hb = (__bf16)v;
        OH[o] = hb;
        OL[o] = (__bf16)(v - (float)hb);
      }
  }
#undef ASTAGE
}

// ---------------------------------------------------------------------------
// Fused ReLU + LayerNorm over rows of 1024. One block (256 thr) per row.
// ---------------------------------------------------------------------------
__global__ __launch_bounds__(256) void relu_ln_k(const float* __restrict__ X,
                                                 const float* __restrict__ gam,
                                                 const float* __restrict__ bta,
                                                 float* __restrict__ out) {
  __shared__ float red[8];
  const int row = blockIdx.x;
  const int tid = threadIdx.x;
  const int c = tid << 2;

  const float4 v = *reinterpret_cast<const float4*>(&X[(size_t)row * HDIM + c]);
  float x[4] = {fmaxf(v.x, 0.f), fmaxf(v.y, 0.f), fmaxf(v.z, 0.f), fmaxf(v.w, 0.f)};
  float sum = x[0] + x[1] + x[2] + x[3];
  float ss = x[0] * x[0] + x[1] * x[1] + x[2] * x[2] + x[3] * x[3];
#pragma unroll
  for (int off = 1; off < 64; off <<= 1) {
    sum += __shfl_xor(sum, off);
    ss += __shfl_xor(ss, off);
  }
  const int wid = tid >> 6;
  if ((tid & 63) == 0) {
    red[wid] = sum;
    red[4 + wid] = ss;
  }
  __syncthreads();
  sum = red[0] + red[1] + red[2] + red[3];
  ss = red[4] + red[5] + red[6] + red[7];
  const float mean = sum * (1.0f / HDIM);
  const float var = ss * (1.0f / HDIM) - mean * mean;
  const float rstd = rsqrtf(var + LN_EPS);

  const float4 gv = *reinterpret_cast<const float4*>(&gam[c]);
  const float4 bv = *reinterpret_cast<const float4*>(&bta[c]);
  float4 o;
  o.x = (x[0] - mean) * rstd * gv.x + bv.x;
  o.y = (x[1] - mean) * rstd * gv.y + bv.y;
  o.z = (x[2] - mean) * rstd * gv.z + bv.z;
  o.w = (x[3] - mean) * rstd * gv.w + bv.w;
  *reinterpret_cast<float4*>(&out[(size_t)row * HDIM + c]) = o;
}

// ---------------------------------------------------------------------------
// Launch. ws (128 MB):
//  [0,16M): wts hi (qw,kw,vw,ow @2MB) + wts lo (@2MB each)
//  [16,48M): QH,QL        -> later proj fp32 (32MB)
//  [48,80M): KH,KL
//  [80,96M): VtH
//  [96,128M): featH,featL -> later attnH,attnL
// ---------------------------------------------------------------------------
extern "C" void kernel_launch(void* const* d_in, const int* in_sizes, int n_in,
                              void* d_out, int out_size, void* d_ws, size_t ws_size,
                              hipStream_t stream) {
  const float* feat = (const float*)d_in[0];
  const float* qw = (const float*)d_in[1];
  const float* qb = (const float*)d_in[2];
  const float* kw = (const float*)d_in[3];
  const float* kb = (const float*)d_in[4];
  const float* vw = (const float*)d_in[5];
  const float* vb = (const float*)d_in[6];
  const float* ow = (const float*)d_in[7];
  const float* ob = (const float*)d_in[8];
  const float* ln_g = (const float*)d_in[9];
  const float* ln_b = (const float*)d_in[10];

  char* ws = (char*)d_ws;
  const size_t MB = 1u << 20;
  __bf16* qwH = (__bf16*)(ws + 0 * MB);
  __bf16* kwH = (__bf16*)(ws + 2 * MB);
  __bf16* vwH = (__bf16*)(ws + 4 * MB);
  __bf16* owH = (__bf16*)(ws + 6 * MB);
  __bf16* qwL = (__bf16*)(ws + 8 * MB);
  __bf16* kwL = (__bf16*)(ws + 10 * MB);
  __bf16* vwL = (__bf16*)(ws + 12 * MB);
  __bf16* owL = (__bf16*)(ws + 14 * MB);
  __bf16* QHp = (__bf16*)(ws + 16 * MB);
  __bf16* QLp = (__bf16*)(ws + 32 * MB);
  __bf16* KHp = (__bf16*)(ws + 48 * MB);
  __bf16* KLp = (__bf16*)(ws + 64 * MB);
  __bf16* VTp = (__bf16*)(ws + 80 * MB);
  __bf16* ftH = (__bf16*)(ws + 96 * MB);
  __bf16* ftL = (__bf16*)(ws + 112 * MB);
  __bf16* atH = ftH;  // reuse after feat dead
  __bf16* atL = ftL;
  float* proj = (float*)(ws + 16 * MB);  // reuse Q region after attention

  // splits
  split_k<<<(MROWS * HDIM / 4 + 255) / 256, 256, 0, stream>>>(feat, ftH, ftL, MROWS * HDIM / 4);
  split_k<<<(HDIM * HDIM / 4 + 255) / 256, 256, 0, stream>>>(qw, qwH, qwL, HDIM * HDIM / 4);
  split_k<<<(HDIM * HDIM / 4 + 255) / 256, 256, 0, stream>>>(kw, kwH, kwL, HDIM * HDIM / 4);
  split_k<<<(HDIM * HDIM / 4 + 255) / 256, 256, 0, stream>>>(vw, vwH, vwL, HDIM * HDIM / 4);
  split_k<<<(HDIM * HDIM / 4 + 255) / 256, 256, 0, stream>>>(ow, owH, owL, HDIM * HDIM / 4);

  const dim3 gg(MROWS / 128, HDIM / 128);
  gemm3p_k<0, 3><<<gg, 256, 0, stream>>>(ftH, ftL, qwH, qwL, qb, QHp, QLp, nullptr);
  gemm3p_k<0, 3><<<gg, 256, 0, stream>>>(ftH, ftL, kwH, kwL, kb, KHp, KLp, nullptr);
  gemm3p_k<1, 2><<<gg, 256, 0, stream>>>(ftH, ftL, vwH, vwL, vb, VTp, nullptr, nullptr);

  attn5_k<<<BATCH * NHEAD * (SEQLEN / 128), 256, 0, stream>>>(QHp, QLp, KHp, KLp, VTp, atH, atL);

  gemm3p_k<2, 2><<<gg, 256, 0, stream>>>(atH, atL, owH, owL, ob, nullptr, nullptr, proj);

  relu_ln_k<<<MROWS, 256, 0, stream>>>(proj, ln_g, ln_b, (float*)d_out);
}

// Round 5
// 451.523 us; speedup vs baseline: 4.8533x; 1.0126x over previous
//
#include <hip/hip_runtime.h>
#include <math.h>

#define HDIM 1024
#define NHEAD 16
#define HEADD 64
#define SEQLEN 2048
#define BATCH 4
#define MROWS (BATCH * SEQLEN)  // 8192
#define LN_EPS 1e-5f
#define QSCALE 2.8853900817779268f  // 2 * log2(e): logits in log2 units

typedef float f32x4 __attribute__((ext_vector_type(4)));
typedef short s16x8 __attribute__((ext_vector_type(8)));
typedef short s16x4 __attribute__((ext_vector_type(4)));
typedef __bf16 bf16x4 __attribute__((ext_vector_type(4)));

#define MFMA16(a, b, c) __builtin_amdgcn_mfma_f32_16x16x32_bf16((a), (b), (c), 0, 0, 0)

#if __has_builtin(__builtin_amdgcn_exp2f)
#define EXP2(x) __builtin_amdgcn_exp2f(x)
#else
#define EXP2(x) exp2f(x)
#endif

__device__ __forceinline__ void load_lds16(const __bf16* g, __bf16* l) {
  __builtin_amdgcn_global_load_lds((const __attribute__((address_space(1))) void*)g,
                                   (__attribute__((address_space(3))) void*)l, 16, 0, 0);
}

// ---------------------------------------------------------------------------
// fp32 -> bf16 (hi, lo) split, 4 elems/thread (feat)
// ---------------------------------------------------------------------------
__global__ __launch_bounds__(256) void split_k(const float* __restrict__ src,
                                               __bf16* __restrict__ h,
                                               __bf16* __restrict__ l, int n4) {
  int i = blockIdx.x * blockDim.x + threadIdx.x;
  if (i >= n4) return;
  float4 v = reinterpret_cast<const float4*>(src)[i];
  bf16x4 hv, lv;
  hv[0] = (__bf16)v.x; hv[1] = (__bf16)v.y; hv[2] = (__bf16)v.z; hv[3] = (__bf16)v.w;
  lv[0] = (__bf16)(v.x - (float)hv[0]);
  lv[1] = (__bf16)(v.y - (float)hv[1]);
  lv[2] = (__bf16)(v.z - (float)hv[2]);
  lv[3] = (__bf16)(v.w - (float)hv[3]);
  reinterpret_cast<bf16x4*>(h)[i] = hv;
  reinterpret_cast<bf16x4*>(l)[i] = lv;
}

// All 4 weight matrices in one launch (blockIdx.y selects matrix).
__global__ __launch_bounds__(256) void wsplit_k(
    const float* __restrict__ w0, const float* __restrict__ w1,
    const float* __restrict__ w2, const float* __restrict__ w3,
    __bf16* __restrict__ h0, __bf16* __restrict__ l0, __bf16* __restrict__ h1,
    __bf16* __restrict__ l1, __bf16* __restrict__ h2, __bf16* __restrict__ l2,
    __bf16* __restrict__ h3, __bf16* __restrict__ l3) {
  const int which = blockIdx.y;
  const float* src = which == 0 ? w0 : which == 1 ? w1 : which == 2 ? w2 : w3;
  __bf16* h = which == 0 ? h0 : which == 1 ? h1 : which == 2 ? h2 : h3;
  __bf16* l = which == 0 ? l0 : which == 1 ? l1 : which == 2 ? l2 : l3;
  const int i = blockIdx.x * blockDim.x + threadIdx.x;
  float4 v = reinterpret_cast<const float4*>(src)[i];
  bf16x4 hv, lv;
  hv[0] = (__bf16)v.x; hv[1] = (__bf16)v.y; hv[2] = (__bf16)v.z; hv[3] = (__bf16)v.w;
  lv[0] = (__bf16)(v.x - (float)hv[0]);
  lv[1] = (__bf16)(v.y - (float)hv[1]);
  lv[2] = (__bf16)(v.z - (float)hv[2]);
  lv[3] = (__bf16)(v.w - (float)hv[3]);
  reinterpret_cast<bf16x4*>(h)[i] = hv;
  reinterpret_cast<bf16x4*>(l)[i] = lv;
}

// ---------------------------------------------------------------------------
// Split-bf16 MFMA GEMM: C = A @ W^T + bias (optionally * scale).
// PASSES==3: AhBh + AhBl + AlBh (Q,K proj — exp-sensitive). LDS 64 KB.
// PASSES==2: AhBh + AlBh (V/out proj). LDS 48 KB -> 3 blocks/CU.
// EPI: 0 = head-layout bf16 hi/lo ; 1 = transposed Vt bf16 hi ; 2 = fp32.
// ---------------------------------------------------------------------------
template <int EPI, int PASSES>
__global__ __launch_bounds__(256, PASSES == 2 ? 3 : 2) void gemm3p_k(
    const __bf16* __restrict__ AH, const __bf16* __restrict__ AL,
    const __bf16* __restrict__ BH, const __bf16* __restrict__ BL,
    const float* __restrict__ bias, const float scale, __bf16* __restrict__ CH,
    __bf16* __restrict__ CL, float* __restrict__ CF) {
  __shared__ __bf16 smem[(PASSES == 3) ? 32768 : 24576];

  const int tid = threadIdx.x;
  const int lane = tid & 63;
  const int w = tid >> 6;
  const int fr = lane & 15;
  const int g = lane >> 4;
  const int wm = w >> 1, wn = w & 1;
  const int m0 = blockIdx.x << 7;
  const int n0 = blockIdx.y << 7;

#define GSTAGE(buf, kt)                                                       \
  do {                                                                        \
    const int ke_ = (kt) * 32 + (lane & 3) * 8;                               \
    _Pragma("unroll") for (int c_ = 0; c_ < 2; ++c_) {                        \
      const int rr_ = 32 * w + 16 * c_ + (lane >> 2);                         \
      const int lo_ = (32 * w + 16 * c_) * 32;                                \
      load_lds16(AH + (size_t)(m0 + rr_) * HDIM + ke_, &smem[(buf)*4096 + lo_]); \
      load_lds16(AL + (size_t)(m0 + rr_) * HDIM + ke_, &smem[8192 + (buf)*4096 + lo_]); \
      load_lds16(BH + (size_t)(n0 + rr_) * HDIM + ke_, &smem[16384 + (buf)*4096 + lo_]); \
      if (PASSES == 3)                                                        \
        load_lds16(BL + (size_t)(n0 + rr_) * HDIM + ke_, &smem[24576 + (buf)*4096 + lo_]); \
    }                                                                         \
  } while (0)

  f32x4 acc[4][4] = {};

  GSTAGE(0, 0);
  __syncthreads();

  for (int kt = 0; kt < HDIM / 32; ++kt) {
    const int buf = kt & 1;
    if (kt + 1 < HDIM / 32) GSTAGE(buf ^ 1, kt + 1);

    s16x8 aH[4], aL[4], bH[4], bL[4];
#pragma unroll
    for (int mi = 0; mi < 4; ++mi) {
      const int off = (wm * 64 + mi * 16 + fr) * 32 + g * 8;
      aH[mi] = *reinterpret_cast<const s16x8*>(&smem[buf * 4096 + off]);
      aL[mi] = *reinterpret_cast<const s16x8*>(&smem[8192 + buf * 4096 + off]);
    }
#pragma unroll
    for (int ni = 0; ni < 4; ++ni) {
      const int off = (wn * 64 + ni * 16 + fr) * 32 + g * 8;
      bH[ni] = *reinterpret_cast<const s16x8*>(&smem[16384 + buf * 4096 + off]);
      if (PASSES == 3)
        bL[ni] = *reinterpret_cast<const s16x8*>(&smem[24576 + buf * 4096 + off]);
    }
#pragma unroll
    for (int mi = 0; mi < 4; ++mi)
#pragma unroll
      for (int ni = 0; ni < 4; ++ni) {
        acc[mi][ni] = MFMA16(aH[mi], bH[ni], acc[mi][ni]);
        if (PASSES == 3) acc[mi][ni] = MFMA16(aH[mi], bL[ni], acc[mi][ni]);
        acc[mi][ni] = MFMA16(aL[mi], bH[ni], acc[mi][ni]);
      }
    __syncthreads();
  }

  float bv[4];
#pragma unroll
  for (int ni = 0; ni < 4; ++ni) bv[ni] = bias[n0 + wn * 64 + ni * 16 + fr];

  if (EPI == 0) {  // head layout [B,NH,S,HD], bf16 hi/lo, scaled
#pragma unroll
    for (int mi = 0; mi < 4; ++mi)
#pragma unroll
      for (int ni = 0; ni < 4; ++ni)
#pragma unroll
        for (int r = 0; r < 4; ++r) {
          const float v = (acc[mi][ni][r] + bv[ni]) * scale;
          const int m = m0 + wm * 64 + mi * 16 + 4 * g + r;
          const int n = n0 + wn * 64 + ni * 16 + fr;
          const int b = m >> 11, s = m & 2047, h = n >> 6, d = n & 63;
          const size_t o = ((size_t)(b * NHEAD + h) * SEQLEN + s) * HEADD + d;
          const __bf16 hb = (__bf16)v;
          CH[o] = hb;
          CL[o] = (__bf16)(v - (float)hb);
        }
  } else if (EPI == 2) {  // plain fp32 [M][H]
#pragma unroll
    for (int mi = 0; mi < 4; ++mi)
#pragma unroll
      for (int ni = 0; ni < 4; ++ni)
#pragma unroll
        for (int r = 0; r < 4; ++r) {
          const int m = m0 + wm * 64 + mi * 16 + 4 * g + r;
          const int n = n0 + wn * 64 + ni * 16 + fr;
          CF[(size_t)m * HDIM + n] = acc[mi][ni][r] + bv[ni];
        }
  } else {  // EPI == 1: transposed Vt [B,NH,HD,S] bf16 hi via LDS transpose
    __syncthreads();
#pragma unroll
    for (int mi = 0; mi < 4; ++mi)
#pragma unroll
      for (int ni = 0; ni < 4; ++ni)
#pragma unroll
        for (int r = 0; r < 4; ++r) {
          const float v = acc[mi][ni][r] + bv[ni];
          const int nl = wn * 64 + ni * 16 + fr;
          const int ml = wm * 64 + mi * 16 + 4 * g + r;
          smem[nl * 128 + (((ml >> 3) ^ (nl & 7)) << 3) + (ml & 7)] = (__bf16)v;
        }
    __syncthreads();
    const int nl = tid >> 1, mh = tid & 1;
    const int b = m0 >> 11, s0 = m0 & 2047;
    const int gn = n0 + nl, h = gn >> 6, d = gn & 63;
#pragma unroll
    for (int j = 0; j < 8; ++j) {
      const int cm = mh * 8 + j;
      s16x8 vv = *reinterpret_cast<const s16x8*>(&smem[nl * 128 + ((cm ^ (nl & 7)) << 3)]);
      const size_t o = ((size_t)((b * NHEAD + h) * HEADD + d)) * SEQLEN + s0 + cm * 8;
      *reinterpret_cast<s16x8*>(&CH[o]) = vv;
    }
  }
#undef GSTAGE
}

// ---------------------------------------------------------------------------
// Flash attention v4: identical data layout to v3, but VALU-lean:
// loop-carried staging pointers, imm-foldable LDS addressing, kt unrolled x2
// (literal buf), exp2-domain softmax (Q pre-scaled by 2*log2e).
// LDS: KH 16K | KL 16K | V 16K (dbuf) | PH 16K = 64 KB.
// ---------------------------------------------------------------------------
__global__ __launch_bounds__(256, 2) void attn6_k(
    const __bf16* __restrict__ QH, const __bf16* __restrict__ QL,
    const __bf16* __restrict__ KH, const __bf16* __restrict__ KL,
    const __bf16* __restrict__ VT, __bf16* __restrict__ OH,
    __bf16* __restrict__ OL) {
  __shared__ __bf16 smem[32768];  // 64 KB

  const int tid = threadIdx.x;
  const int lane = tid & 63;
  const int w = tid >> 6;
  const int fr = lane & 15;
  const int g = lane >> 4;
  const int f7 = fr & 7;

  // XCD swizzle: concurrent blocks on one XCD share few bh (KV L2 locality)
  const int blk = blockIdx.x;
  const int xcd = blk & 7, idx = blk >> 3;  // grid = 1024
  const int bh = xcd * 8 + (idx >> 4);      // 64 bh
  const int qt = idx & 15;                  // 16 q-tiles of 128
  const int q0 = qt << 7;
  const size_t bhO = (size_t)bh * SEQLEN * HEADD;

  // Q fragments (B-operand), pre-scaled to log2 domain by the projection.
  s16x8 qHf[2][2], qLf[2][2];
#pragma unroll
  for (int qb = 0; qb < 2; ++qb) {
    const size_t qoff = bhO + (size_t)(q0 + w * 32 + qb * 16 + fr) * HEADD;
#pragma unroll
    for (int ks = 0; ks < 2; ++ks) {
      qHf[qb][ks] = *reinterpret_cast<const s16x8*>(&QH[qoff + ks * 32 + g * 8]);
      qLf[qb][ks] = *reinterpret_cast<const s16x8*>(&QL[qoff + ks * 32 + g * 8]);
    }
  }

  // ---- loop-carried staging state (6 streams/thread) ----
  const __bf16* gsrc[6];
  int gstep[6], ldoff[6];
  {
    const int rsub = lane >> 3;
    const int ch = (lane & 7) ^ rsub;
#pragma unroll
    for (int i_ = 0; i_ < 6; ++i_) {
      const int L_ = w * 6 + i_;
      const int t_ = L_ >> 3, sub_ = L_ & 7;
      ldoff[i_] = t_ * 8192 + sub_ * 512;
      if (t_ < 2) {
        const __bf16* base_ = (t_ == 0) ? KH : KL;
        gsrc[i_] = base_ + bhO + (size_t)(sub_ * 8 + rsub) * HEADD + ch * 8;
        gstep[i_] = 64 * HEADD;
      } else {
        gsrc[i_] = VT + ((size_t)bh * HEADD + sub_ * 8 + rsub) * SEQLEN + ch * 8;
        gstep[i_] = 64;
      }
    }
  }

#define ASTAGE(bufl)                                              \
  do {                                                            \
    _Pragma("unroll") for (int i_ = 0; i_ < 6; ++i_) {            \
      load_lds16(gsrc[i_], &smem[ldoff[i_] + (bufl)*4096]);       \
      gsrc[i_] += gstep[i_];                                      \
    }                                                             \
  } while (0)

  // ---- precomputed LDS element-index bases ----
  const int rb0 = fr * 64 + ((g ^ f7) << 3);              // ks=0 chunk
  const int rb1 = fr * 64 + (((4 + g) ^ f7) << 3);        // ks=1 chunk
  const int prbase = 24576 + w * 2048;                    // P read: +qb*1024+rb
  const int pwbase = 24576 + w * 2048 + fr * 64 + (g & 1) * 4;
  int pco[4];
#pragma unroll
  for (int kb = 0; kb < 4; ++kb) pco[kb] = ((2 * kb + (g >> 1)) ^ f7) << 3;

  f32x4 oacc0[4] = {}, oacc1[4] = {};
  float m0r = -1e30f, m1r = -1e30f, l0r = 0.f, l1r = 0.f;

  auto process = [&](const int B) {
    // ---- S^T = K Q^T (3-pass split); log2-domain scores ----
    f32x4 sf0[4] = {}, sf1[4] = {};
    __builtin_amdgcn_s_setprio(1);
#pragma unroll
    for (int kb = 0; kb < 4; ++kb) {
      const s16x8 kh0 = *reinterpret_cast<const s16x8*>(&smem[B * 4096 + kb * 1024 + rb0]);
      const s16x8 kl0 = *reinterpret_cast<const s16x8*>(&smem[8192 + B * 4096 + kb * 1024 + rb0]);
      const s16x8 kh1 = *reinterpret_cast<const s16x8*>(&smem[B * 4096 + kb * 1024 + rb1]);
      const s16x8 kl1 = *reinterpret_cast<const s16x8*>(&smem[8192 + B * 4096 + kb * 1024 + rb1]);
      sf0[kb] = MFMA16(kh0, qHf[0][0], sf0[kb]);
      sf0[kb] = MFMA16(kl0, qHf[0][0], sf0[kb]);
      sf0[kb] = MFMA16(kh0, qLf[0][0], sf0[kb]);
      sf0[kb] = MFMA16(kh1, qHf[0][1], sf0[kb]);
      sf0[kb] = MFMA16(kl1, qHf[0][1], sf0[kb]);
      sf0[kb] = MFMA16(kh1, qLf[0][1], sf0[kb]);
      sf1[kb] = MFMA16(kh0, qHf[1][0], sf1[kb]);
      sf1[kb] = MFMA16(kl0, qHf[1][0], sf1[kb]);
      sf1[kb] = MFMA16(kh0, qLf[1][0], sf1[kb]);
      sf1[kb] = MFMA16(kh1, qHf[1][1], sf1[kb]);
      sf1[kb] = MFMA16(kl1, qHf[1][1], sf1[kb]);
      sf1[kb] = MFMA16(kh1, qLf[1][1], sf1[kb]);
    }
    __builtin_amdgcn_s_setprio(0);

    // ---- online softmax (exp2 domain), lane-local ----
    float mx0 = sf0[0][0], mx1 = sf1[0][0];
#pragma unroll
    for (int kb = 0; kb < 4; ++kb)
#pragma unroll
      for (int r = 0; r < 4; ++r) {
        mx0 = fmaxf(mx0, sf0[kb][r]);
        mx1 = fmaxf(mx1, sf1[kb][r]);
      }
    mx0 = fmaxf(mx0, __shfl_xor(mx0, 16));
    mx0 = fmaxf(mx0, __shfl_xor(mx0, 32));
    mx1 = fmaxf(mx1, __shfl_xor(mx1, 16));
    mx1 = fmaxf(mx1, __shfl_xor(mx1, 32));
    const bool ok = (mx0 <= m0r + 11.5f) && (mx1 <= m1r + 11.5f);
    if (!__all(ok)) {  // rescale path (rare after warm-up)
      const float mn0 = fmaxf(m0r, mx0), mn1 = fmaxf(m1r, mx1);
      const float c0 = EXP2(m0r - mn0), c1 = EXP2(m1r - mn1);
      m0r = mn0; m1r = mn1;
      l0r *= c0; l1r *= c1;
      float cr0[4], cr1[4];
#pragma unroll
      for (int r = 0; r < 4; ++r) {
        cr0[r] = __shfl(c0, 4 * g + r);
        cr1[r] = __shfl(c1, 4 * g + r);
      }
#pragma unroll
      for (int di = 0; di < 4; ++di)
#pragma unroll
        for (int r = 0; r < 4; ++r) {
          oacc0[di][r] *= cr0[r];
          oacc1[di][r] *= cr1[r];
        }
    }
    float ps0 = 0.f, ps1 = 0.f;
#pragma unroll
    for (int kb = 0; kb < 4; ++kb)
#pragma unroll
      for (int r = 0; r < 4; ++r) {
        const float p0 = EXP2(sf0[kb][r] - m0r);
        const float p1 = EXP2(sf1[kb][r] - m1r);
        sf0[kb][r] = p0;
        sf1[kb][r] = p1;
        ps0 += p0;
        ps1 += p1;
      }
    ps0 += __shfl_xor(ps0, 16);
    ps0 += __shfl_xor(ps0, 32);
    ps1 += __shfl_xor(ps1, 16);
    ps1 += __shfl_xor(ps1, 32);
    l0r += ps0;
    l1r += ps1;

    // ---- P (hi) -> LDS as packed b64 ----
#pragma unroll
    for (int kb = 0; kb < 4; ++kb) {
      s16x4 h0, h1;
#pragma unroll
      for (int r = 0; r < 4; ++r) {
        h0[r] = __builtin_bit_cast(short, (__bf16)sf0[kb][r]);
        h1[r] = __builtin_bit_cast(short, (__bf16)sf1[kb][r]);
      }
      *reinterpret_cast<s16x4*>(&smem[pwbase + pco[kb]]) = h0;
      *reinterpret_cast<s16x4*>(&smem[pwbase + 1024 + pco[kb]]) = h1;
    }

    // ---- O += P @ V (single pass), within-wave P readback ----
    __builtin_amdgcn_s_setprio(1);
#pragma unroll
    for (int ks = 0; ks < 2; ++ks) {
      const int rbv = ks ? rb1 : rb0;
      const s16x8 p0 = *reinterpret_cast<const s16x8*>(&smem[prbase + rbv]);
      const s16x8 p1 = *reinterpret_cast<const s16x8*>(&smem[prbase + 1024 + rbv]);
#pragma unroll
      for (int di = 0; di < 4; ++di) {
        const s16x8 vf = *reinterpret_cast<const s16x8*>(
            &smem[16384 + B * 4096 + di * 1024 + rbv]);
        oacc0[di] = MFMA16(p0, vf, oacc0[di]);
        oacc1[di] = MFMA16(p1, vf, oacc1[di]);
      }
    }
    __builtin_amdgcn_s_setprio(0);
  };

  ASTAGE(0);
  __syncthreads();
  for (int kt = 0; kt < SEQLEN / 64 - 2; kt += 2) {
    ASTAGE(1);
    process(0);
    __syncthreads();
    ASTAGE(0);
    process(1);
    __syncthreads();
  }
  ASTAGE(1);
  process(0);
  __syncthreads();
  process(1);

  // ---- epilogue: normalize (l lives in fr-domain -> shfl to 4g+r), write ----
  const int b = bh >> 4, h = bh & 15;
  const float inv0 = 1.0f / l0r, inv1 = 1.0f / l1r;
  float iv0[4], iv1[4];
#pragma unroll
  for (int r = 0; r < 4; ++r) {
    iv0[r] = __shfl(inv0, 4 * g + r);
    iv1[r] = __shfl(inv1, 4 * g + r);
  }
#pragma unroll
  for (int di = 0; di < 4; ++di)
#pragma unroll
    for (int r = 0; r < 4; ++r) {
      const int srow = q0 + w * 32 + 4 * g + r;
      const size_t o0 = ((size_t)b * SEQLEN + srow) * HDIM + h * 64 + di * 16 + fr;
      const size_t o1 = o0 + 16 * HDIM;  // qb=1 rows are +16
      const float v0 = oacc0[di][r] * iv0[r];
      const float v1 = oacc1[di][r] * iv1[r];
      const __bf16 hb0 = (__bf16)v0;
      const __bf16 hb1 = (__bf16)v1;
      OH[o0] = hb0;
      OL[o0] = (__bf16)(v0 - (float)hb0);
      OH[o1] = hb1;
      OL[o1] = (__bf16)(v1 - (float)hb1);
    }
#undef ASTAGE
}

// ---------------------------------------------------------------------------
// Fused ReLU + LayerNorm over rows of 1024. One block (256 thr) per row.
// ---------------------------------------------------------------------------
__global__ __launch_bounds__(256) void relu_ln_k(const float* __restrict__ X,
                                                 const float* __restrict__ gam,
                                                 const float* __restrict__ bta,
                                                 float* __restrict__ out) {
  __shared__ float red[8];
  const int row = blockIdx.x;
  const int tid = threadIdx.x;
  const int c = tid << 2;

  const float4 v = *reinterpret_cast<const float4*>(&X[(size_t)row * HDIM + c]);
  float x[4] = {fmaxf(v.x, 0.f), fmaxf(v.y, 0.f), fmaxf(v.z, 0.f), fmaxf(v.w, 0.f)};
  float sum = x[0] + x[1] + x[2] + x[3];
  float ss = x[0] * x[0] + x[1] * x[1] + x[2] * x[2] + x[3] * x[3];
#pragma unroll
  for (int off = 1; off < 64; off <<= 1) {
    sum += __shfl_xor(sum, off);
    ss += __shfl_xor(ss, off);
  }
  const int wid = tid >> 6;
  if ((tid & 63) == 0) {
    red[wid] = sum;
    red[4 + wid] = ss;
  }
  __syncthreads();
  sum = red[0] + red[1] + red[2] + red[3];
  ss = red[4] + red[5] + red[6] + red[7];
  const float mean = sum * (1.0f / HDIM);
  const float var = ss * (1.0f / HDIM) - mean * mean;
  const float rstd = rsqrtf(var + LN_EPS);

  const float4 gv = *reinterpret_cast<const float4*>(&gam[c]);
  const float4 bv = *reinterpret_cast<const float4*>(&bta[c]);
  float4 o;
  o.x = (x[0] - mean) * rstd * gv.x + bv.x;
  o.y = (x[1] - mean) * rstd * gv.y + bv.y;
  o.z = (x[2] - mean) * rstd * gv.z + bv.z;
  o.w = (x[3] - mean) * rstd * gv.w + bv.w;
  *reinterpret_cast<float4*>(&out[(size_t)row * HDIM + c]) = o;
}

// ---------------------------------------------------------------------------
// Launch. ws (128 MB):
//  [0,16M): wts hi (qw,kw,vw,ow @2MB) + wts lo (@2MB each)
//  [16,48M): QH,QL        -> later proj fp32 (32MB)
//  [48,80M): KH,KL
//  [80,96M): VtH
//  [96,128M): featH,featL -> later attnH,attnL
// ---------------------------------------------------------------------------
extern "C" void kernel_launch(void* const* d_in, const int* in_sizes, int n_in,
                              void* d_out, int out_size, void* d_ws, size_t ws_size,
                              hipStream_t stream) {
  const float* feat = (const float*)d_in[0];
  const float* qw = (const float*)d_in[1];
  const float* qb = (const float*)d_in[2];
  const float* kw = (const float*)d_in[3];
  const float* kb = (const float*)d_in[4];
  const float* vw = (const float*)d_in[5];
  const float* vb = (const float*)d_in[6];
  const float* ow = (const float*)d_in[7];
  const float* ob = (const float*)d_in[8];
  const float* ln_g = (const float*)d_in[9];
  const float* ln_b = (const float*)d_in[10];

  char* ws = (char*)d_ws;
  const size_t MB = 1u << 20;
  __bf16* qwH = (__bf16*)(ws + 0 * MB);
  __bf16* kwH = (__bf16*)(ws + 2 * MB);
  __bf16* vwH = (__bf16*)(ws + 4 * MB);
  __bf16* owH = (__bf16*)(ws + 6 * MB);
  __bf16* qwL = (__bf16*)(ws + 8 * MB);
  __bf16* kwL = (__bf16*)(ws + 10 * MB);
  __bf16* vwL = (__bf16*)(ws + 12 * MB);
  __bf16* owL = (__bf16*)(ws + 14 * MB);
  __bf16* QHp = (__bf16*)(ws + 16 * MB);
  __bf16* QLp = (__bf16*)(ws + 32 * MB);
  __bf16* KHp = (__bf16*)(ws + 48 * MB);
  __bf16* KLp = (__bf16*)(ws + 64 * MB);
  __bf16* VTp = (__bf16*)(ws + 80 * MB);
  __bf16* ftH = (__bf16*)(ws + 96 * MB);
  __bf16* ftL = (__bf16*)(ws + 112 * MB);
  __bf16* atH = ftH;  // reuse after feat dead
  __bf16* atL = ftL;
  float* proj = (float*)(ws + 16 * MB);  // reuse Q region after attention

  // splits
  split_k<<<(MROWS * HDIM / 4 + 255) / 256, 256, 0, stream>>>(feat, ftH, ftL,
                                                              MROWS * HDIM / 4);
  wsplit_k<<<dim3(HDIM * HDIM / 4 / 256, 4), 256, 0, stream>>>(
      qw, kw, vw, ow, qwH, qwL, kwH, kwL, vwH, vwL, owH, owL);

  const dim3 gg(MROWS / 128, HDIM / 128);
  gemm3p_k<0, 3><<<gg, 256, 0, stream>>>(ftH, ftL, qwH, qwL, qb, QSCALE, QHp, QLp, nullptr);
  gemm3p_k<0, 3><<<gg, 256, 0, stream>>>(ftH, ftL, kwH, kwL, kb, 1.0f, KHp, KLp, nullptr);
  gemm3p_k<1, 2><<<gg, 256, 0, stream>>>(ftH, ftL, vwH, vwL, vb, 1.0f, VTp, nullptr, nullptr);

  attn6_k<<<BATCH * NHEAD * (SEQLEN / 128), 256, 0, stream>>>(QHp, QLp, KHp, KLp,
                                                              VTp, atH, atL);

  gemm3p_k<2, 2><<<gg, 256, 0, stream>>>(atH, atL, owH, owL, ob, 1.0f, nullptr,
                                         nullptr, proj);

  relu_ln_k<<<MROWS, 256, 0, stream>>>(proj, ln_g, ln_b, (float*)d_out);
}

// Round 7
// 443.947 us; speedup vs baseline: 4.9361x; 1.0171x over previous
//
#include <hip/hip_runtime.h>
#include <math.h>

#define HDIM 1024
#define NHEAD 16
#define HEADD 64
#define SEQLEN 2048
#define BATCH 4
#define MROWS (BATCH * SEQLEN)  // 8192
#define LN_EPS 1e-5f
#define QSCALE 2.8853900817779268f  // 2 * log2(e): logits in log2 units

typedef float f32x4 __attribute__((ext_vector_type(4)));
typedef short s16x8 __attribute__((ext_vector_type(8)));
typedef short s16x4 __attribute__((ext_vector_type(4)));
typedef __bf16 bf16x4 __attribute__((ext_vector_type(4)));

#define MFMA16(a, b, c) __builtin_amdgcn_mfma_f32_16x16x32_bf16((a), (b), (c), 0, 0, 0)

#if __has_builtin(__builtin_amdgcn_exp2f)
#define EXP2(x) __builtin_amdgcn_exp2f(x)
#else
#define EXP2(x) exp2f(x)
#endif

__device__ __forceinline__ void load_lds16(const __bf16* g, __bf16* l) {
  __builtin_amdgcn_global_load_lds((const __attribute__((address_space(1))) void*)g,
                                   (__attribute__((address_space(3))) void*)l, 16, 0, 0);
}

// ---------------------------------------------------------------------------
// fp32 -> bf16 (hi, lo) split, 4 elems/thread (feat)
// ---------------------------------------------------------------------------
__global__ __launch_bounds__(256) void split_k(const float* __restrict__ src,
                                               __bf16* __restrict__ h,
                                               __bf16* __restrict__ l, int n4) {
  int i = blockIdx.x * blockDim.x + threadIdx.x;
  if (i >= n4) return;
  float4 v = reinterpret_cast<const float4*>(src)[i];
  bf16x4 hv, lv;
  hv[0] = (__bf16)v.x; hv[1] = (__bf16)v.y; hv[2] = (__bf16)v.z; hv[3] = (__bf16)v.w;
  lv[0] = (__bf16)(v.x - (float)hv[0]);
  lv[1] = (__bf16)(v.y - (float)hv[1]);
  lv[2] = (__bf16)(v.z - (float)hv[2]);
  lv[3] = (__bf16)(v.w - (float)hv[3]);
  reinterpret_cast<bf16x4*>(h)[i] = hv;
  reinterpret_cast<bf16x4*>(l)[i] = lv;
}

// All 4 weight matrices in one launch (blockIdx.y selects matrix).
__global__ __launch_bounds__(256) void wsplit_k(
    const float* __restrict__ w0, const float* __restrict__ w1,
    const float* __restrict__ w2, const float* __restrict__ w3,
    __bf16* __restrict__ h0, __bf16* __restrict__ l0, __bf16* __restrict__ h1,
    __bf16* __restrict__ l1, __bf16* __restrict__ h2, __bf16* __restrict__ l2,
    __bf16* __restrict__ h3, __bf16* __restrict__ l3) {
  const int which = blockIdx.y;
  const float* src = which == 0 ? w0 : which == 1 ? w1 : which == 2 ? w2 : w3;
  __bf16* h = which == 0 ? h0 : which == 1 ? h1 : which == 2 ? h2 : h3;
  __bf16* l = which == 0 ? l0 : which == 1 ? l1 : which == 2 ? l2 : l3;
  const int i = blockIdx.x * blockDim.x + threadIdx.x;
  float4 v = reinterpret_cast<const float4*>(src)[i];
  bf16x4 hv, lv;
  hv[0] = (__bf16)v.x; hv[1] = (__bf16)v.y; hv[2] = (__bf16)v.z; hv[3] = (__bf16)v.w;
  lv[0] = (__bf16)(v.x - (float)hv[0]);
  lv[1] = (__bf16)(v.y - (float)hv[1]);
  lv[2] = (__bf16)(v.z - (float)hv[2]);
  lv[3] = (__bf16)(v.w - (float)hv[3]);
  reinterpret_cast<bf16x4*>(h)[i] = hv;
  reinterpret_cast<bf16x4*>(l)[i] = lv;
}

// ---------------------------------------------------------------------------
// Split-bf16 MFMA GEMM: C = A @ W^T + bias (optionally * scale).
// PASSES==3: AhBh + AhBl + AlBh (Q,K proj — exp-sensitive). LDS 64 KB.
// PASSES==2: AhBh + AlBh (V/out proj). LDS 48 KB.
// EPI: 0 = head-layout bf16 hi/lo ; 1 = transposed Vt bf16 hi ; 2 = fp32.
// ---------------------------------------------------------------------------
template <int EPI, int PASSES>
__global__ __launch_bounds__(256, 2) void gemm3p_k(
    const __bf16* __restrict__ AH, const __bf16* __restrict__ AL,
    const __bf16* __restrict__ BH, const __bf16* __restrict__ BL,
    const float* __restrict__ bias, const float scale, __bf16* __restrict__ CH,
    __bf16* __restrict__ CL, float* __restrict__ CF) {
  __shared__ __bf16 smem[(PASSES == 3) ? 32768 : 24576];

  const int tid = threadIdx.x;
  const int lane = tid & 63;
  const int w = tid >> 6;
  const int fr = lane & 15;
  const int g = lane >> 4;
  const int wm = w >> 1, wn = w & 1;
  const int m0 = blockIdx.x << 7;
  const int n0 = blockIdx.y << 7;

#define GSTAGE(buf, kt)                                                       \
  do {                                                                        \
    const int ke_ = (kt) * 32 + (lane & 3) * 8;                               \
    _Pragma("unroll") for (int c_ = 0; c_ < 2; ++c_) {                        \
      const int rr_ = 32 * w + 16 * c_ + (lane >> 2);                         \
      const int lo_ = (32 * w + 16 * c_) * 32;                                \
      load_lds16(AH + (size_t)(m0 + rr_) * HDIM + ke_, &smem[(buf)*4096 + lo_]); \
      load_lds16(AL + (size_t)(m0 + rr_) * HDIM + ke_, &smem[8192 + (buf)*4096 + lo_]); \
      load_lds16(BH + (size_t)(n0 + rr_) * HDIM + ke_, &smem[16384 + (buf)*4096 + lo_]); \
      if (PASSES == 3)                                                        \
        load_lds16(BL + (size_t)(n0 + rr_) * HDIM + ke_, &smem[24576 + (buf)*4096 + lo_]); \
    }                                                                         \
  } while (0)

  f32x4 acc[4][4] = {};

  GSTAGE(0, 0);
  __syncthreads();

  for (int kt = 0; kt < HDIM / 32; ++kt) {
    const int buf = kt & 1;
    if (kt + 1 < HDIM / 32) GSTAGE(buf ^ 1, kt + 1);

    s16x8 aH[4], aL[4], bH[4], bL[4];
#pragma unroll
    for (int mi = 0; mi < 4; ++mi) {
      const int off = (wm * 64 + mi * 16 + fr) * 32 + g * 8;
      aH[mi] = *reinterpret_cast<const s16x8*>(&smem[buf * 4096 + off]);
      aL[mi] = *reinterpret_cast<const s16x8*>(&smem[8192 + buf * 4096 + off]);
    }
#pragma unroll
    for (int ni = 0; ni < 4; ++ni) {
      const int off = (wn * 64 + ni * 16 + fr) * 32 + g * 8;
      bH[ni] = *reinterpret_cast<const s16x8*>(&smem[16384 + buf * 4096 + off]);
      if (PASSES == 3)
        bL[ni] = *reinterpret_cast<const s16x8*>(&smem[24576 + buf * 4096 + off]);
    }
#pragma unroll
    for (int mi = 0; mi < 4; ++mi)
#pragma unroll
      for (int ni = 0; ni < 4; ++ni) {
        acc[mi][ni] = MFMA16(aH[mi], bH[ni], acc[mi][ni]);
        if (PASSES == 3) acc[mi][ni] = MFMA16(aH[mi], bL[ni], acc[mi][ni]);
        acc[mi][ni] = MFMA16(aL[mi], bH[ni], acc[mi][ni]);
      }
    __syncthreads();
  }

  float bv[4];
#pragma unroll
  for (int ni = 0; ni < 4; ++ni) bv[ni] = bias[n0 + wn * 64 + ni * 16 + fr];

  if (EPI == 0) {  // head layout [B,NH,S,HD], bf16 hi/lo, scaled
#pragma unroll
    for (int mi = 0; mi < 4; ++mi)
#pragma unroll
      for (int ni = 0; ni < 4; ++ni)
#pragma unroll
        for (int r = 0; r < 4; ++r) {
          const float v = (acc[mi][ni][r] + bv[ni]) * scale;
          const int m = m0 + wm * 64 + mi * 16 + 4 * g + r;
          const int n = n0 + wn * 64 + ni * 16 + fr;
          const int b = m >> 11, s = m & 2047, h = n >> 6, d = n & 63;
          const size_t o = ((size_t)(b * NHEAD + h) * SEQLEN + s) * HEADD + d;
          const __bf16 hb = (__bf16)v;
          CH[o] = hb;
          CL[o] = (__bf16)(v - (float)hb);
        }
  } else if (EPI == 2) {  // plain fp32 [M][H]
#pragma unroll
    for (int mi = 0; mi < 4; ++mi)
#pragma unroll
      for (int ni = 0; ni < 4; ++ni)
#pragma unroll
        for (int r = 0; r < 4; ++r) {
          const int m = m0 + wm * 64 + mi * 16 + 4 * g + r;
          const int n = n0 + wn * 64 + ni * 16 + fr;
          CF[(size_t)m * HDIM + n] = acc[mi][ni][r] + bv[ni];
        }
  } else {  // EPI == 1: transposed Vt [B,NH,HD,S] bf16 hi via LDS transpose
    __syncthreads();
#pragma unroll
    for (int mi = 0; mi < 4; ++mi)
#pragma unroll
      for (int ni = 0; ni < 4; ++ni)
#pragma unroll
        for (int r = 0; r < 4; ++r) {
          const float v = acc[mi][ni][r] + bv[ni];
          const int nl = wn * 64 + ni * 16 + fr;
          const int ml = wm * 64 + mi * 16 + 4 * g + r;
          smem[nl * 128 + (((ml >> 3) ^ (nl & 7)) << 3) + (ml & 7)] = (__bf16)v;
        }
    __syncthreads();
    const int nl = tid >> 1, mh = tid & 1;
    const int b = m0 >> 11, s0 = m0 & 2047;
    const int gn = n0 + nl, h = gn >> 6, d = gn & 63;
#pragma unroll
    for (int j = 0; j < 8; ++j) {
      const int cm = mh * 8 + j;
      s16x8 vv = *reinterpret_cast<const s16x8*>(&smem[nl * 128 + ((cm ^ (nl & 7)) << 3)]);
      const size_t o = ((size_t)((b * NHEAD + h) * HEADD + d)) * SEQLEN + s0 + cm * 8;
      *reinterpret_cast<s16x8*>(&CH[o]) = vv;
    }
  }
#undef GSTAGE
}

// ---------------------------------------------------------------------------
// Flash attention v5: key-permuted swapped QK^T makes the PV A-operand
// LANE-LOCAL — P never touches LDS (packed bf16 in registers).
// sigma(kb*16+4g+r) = (kb>>1)*32 + g*8 + (kb&1)*4 + r; K staging chunk-XOR
// s(row) = ((row>>3&3)<<1)|(row&1) matches the permuted row reads (both-sides
// swizzle). V layout unchanged. LDS: KH|KL|V dbuf = 48 KB -> 3 blocks/CU.
// ---------------------------------------------------------------------------
__global__ __launch_bounds__(256, 3) void attn7_k(
    const __bf16* __restrict__ QH, const __bf16* __restrict__ QL,
    const __bf16* __restrict__ KH, const __bf16* __restrict__ KL,
    const __bf16* __restrict__ VT, __bf16* __restrict__ OH,
    __bf16* __restrict__ OL) {
  __shared__ __bf16 smem[24576];  // 48 KB

  const int tid = threadIdx.x;
  const int lane = tid & 63;
  const int w = tid >> 6;
  const int fr = lane & 15;
  const int g = lane >> 4;
  const int f7 = fr & 7;

  // XCD swizzle: concurrent blocks on one XCD share few bh (KV L2 locality)
  const int blk = blockIdx.x;
  const int xcd = blk & 7, idx = blk >> 3;  // grid = 1024
  const int bh = xcd * 8 + (idx >> 4);      // 64 bh
  const int qt = idx & 15;                  // 16 q-tiles of 128
  const int q0 = qt << 7;
  const size_t bhO = (size_t)bh * SEQLEN * HEADD;

  // Q fragments (B-operand), pre-scaled to log2 domain by the projection.
  s16x8 qHf[2][2], qLf[2][2];
#pragma unroll
  for (int qb = 0; qb < 2; ++qb) {
    const size_t qoff = bhO + (size_t)(q0 + w * 32 + qb * 16 + fr) * HEADD;
#pragma unroll
    for (int ks = 0; ks < 2; ++ks) {
      qHf[qb][ks] = *reinterpret_cast<const s16x8*>(&QH[qoff + ks * 32 + g * 8]);
      qLf[qb][ks] = *reinterpret_cast<const s16x8*>(&QL[qoff + ks * 32 + g * 8]);
    }
  }

  // ---- loop-carried staging state (6 streams/thread) ----
  const __bf16* gsrc[6];
  int gstep[6], ldoff[6];
  {
    const int rsub = lane >> 3;
    const int l7 = lane & 7;
#pragma unroll
    for (int i_ = 0; i_ < 6; ++i_) {
      const int L_ = w * 6 + i_;
      const int t_ = L_ >> 3, sub_ = L_ & 7;
      ldoff[i_] = t_ * 8192 + sub_ * 512;
      if (t_ < 2) {
        const __bf16* base_ = (t_ == 0) ? KH : KL;
        const int ch_ = l7 ^ (((sub_ & 3) << 1) | (rsub & 1));  // s(row) swz
        gsrc[i_] = base_ + bhO + (size_t)(sub_ * 8 + rsub) * HEADD + ch_ * 8;
        gstep[i_] = 64 * HEADD;
      } else {
        const int ch_ = l7 ^ rsub;  // V: d&7 swz (unchanged)
        gsrc[i_] = VT + ((size_t)bh * HEADD + sub_ * 8 + rsub) * SEQLEN + ch_ * 8;
        gstep[i_] = 64;
      }
    }
  }

#define ASTAGE(bufl)                                              \
  do {                                                            \
    _Pragma("unroll") for (int i_ = 0; i_ < 6; ++i_) {            \
      load_lds16(gsrc[i_], &smem[ldoff[i_] + (bufl)*4096]);       \
      gsrc[i_] += gstep[i_];                                      \
    }                                                             \
  } while (0)

  // ---- precomputed LDS element-index bases ----
  // K reads (permuted rows): row kr = (kb>>1)*32 + (fr>>2)*8 + (kb&1)*4 + (fr&3)
  // slot = g ^ s(kr), s(kr) = ((fr>>2)<<1)|(fr&1)  (kb-independent)
  const int sK = ((fr >> 2) << 1) | (fr & 1);
  const int rbk0 = ((fr >> 2) * 8 + (fr & 3)) * 64 + ((g ^ sK) << 3);
  const int rbk1 = rbk0 ^ 32;  // ks=1 chunk (slot^4)
  // V reads (unchanged layout)
  const int rbv0 = fr * 64 + ((g ^ f7) << 3);
  const int rbv1 = rbv0 ^ 32;

  f32x4 oacc0[4] = {}, oacc1[4] = {};
  float m0r = -1e30f, m1r = -1e30f, l0r = 0.f, l1r = 0.f;

  auto process = [&](const int B) {
    // ---- S^T = K Q^T (3-pass split); sf{qb}[kb][r] = score for
    //      key = (kb>>1)*32 + g*8 + (kb&1)*4 + r, q-col = fr ----
    f32x4 sf0[4] = {}, sf1[4] = {};
    __builtin_amdgcn_s_setprio(1);
#pragma unroll
    for (int kb = 0; kb < 4; ++kb) {
      const int ko = (kb & 1) * 256 + (kb >> 1) * 2048;
      const s16x8 kh0 = *reinterpret_cast<const s16x8*>(&smem[B * 4096 + ko + rbk0]);
      const s16x8 kl0 = *reinterpret_cast<const s16x8*>(&smem[8192 + B * 4096 + ko + rbk0]);
      const s16x8 kh1 = *reinterpret_cast<const s16x8*>(&smem[B * 4096 + ko + rbk1]);
      const s16x8 kl1 = *reinterpret_cast<const s16x8*>(&smem[8192 + B * 4096 + ko + rbk1]);
      sf0[kb] = MFMA16(kh0, qHf[0][0], sf0[kb]);
      sf0[kb] = MFMA16(kl0, qHf[0][0], sf0[kb]);
      sf0[kb] = MFMA16(kh0, qLf[0][0], sf0[kb]);
      sf0[kb] = MFMA16(kh1, qHf[0][1], sf0[kb]);
      sf0[kb] = MFMA16(kl1, qHf[0][1], sf0[kb]);
      sf0[kb] = MFMA16(kh1, qLf[0][1], sf0[kb]);
      sf1[kb] = MFMA16(kh0, qHf[1][0], sf1[kb]);
      sf1[kb] = MFMA16(kl0, qHf[1][0], sf1[kb]);
      sf1[kb] = MFMA16(kh0, qLf[1][0], sf1[kb]);
      sf1[kb] = MFMA16(kh1, qHf[1][1], sf1[kb]);
      sf1[kb] = MFMA16(kl1, qHf[1][1], sf1[kb]);
      sf1[kb] = MFMA16(kh1, qLf[1][1], sf1[kb]);
    }
    __builtin_amdgcn_s_setprio(0);

    // ---- online softmax (exp2 domain), lane-local ----
    float mx0 = sf0[0][0], mx1 = sf1[0][0];
#pragma unroll
    for (int kb = 0; kb < 4; ++kb)
#pragma unroll
      for (int r = 0; r < 4; ++r) {
        mx0 = fmaxf(mx0, sf0[kb][r]);
        mx1 = fmaxf(mx1, sf1[kb][r]);
      }
    mx0 = fmaxf(mx0, __shfl_xor(mx0, 16));
    mx0 = fmaxf(mx0, __shfl_xor(mx0, 32));
    mx1 = fmaxf(mx1, __shfl_xor(mx1, 16));
    mx1 = fmaxf(mx1, __shfl_xor(mx1, 32));
    const bool ok = (mx0 <= m0r + 11.5f) && (mx1 <= m1r + 11.5f);
    if (!__all(ok)) {  // rescale path (rare after warm-up)
      const float mn0 = fmaxf(m0r, mx0), mn1 = fmaxf(m1r, mx1);
      const float c0 = EXP2(m0r - mn0), c1 = EXP2(m1r - mn1);
      m0r = mn0; m1r = mn1;
      l0r *= c0; l1r *= c1;
      float cr0[4], cr1[4];
#pragma unroll
      for (int r = 0; r < 4; ++r) {
        cr0[r] = __shfl(c0, 4 * g + r);
        cr1[r] = __shfl(c1, 4 * g + r);
      }
#pragma unroll
      for (int di = 0; di < 4; ++di)
#pragma unroll
        for (int r = 0; r < 4; ++r) {
          oacc0[di][r] *= cr0[r];
          oacc1[di][r] *= cr1[r];
        }
    }
    float ps0 = 0.f, ps1 = 0.f;
#pragma unroll
    for (int kb = 0; kb < 4; ++kb)
#pragma unroll
      for (int r = 0; r < 4; ++r) {
        const float p0 = EXP2(sf0[kb][r] - m0r);
        const float p1 = EXP2(sf1[kb][r] - m1r);
        sf0[kb][r] = p0;
        sf1[kb][r] = p1;
        ps0 += p0;
        ps1 += p1;
      }
    ps0 += __shfl_xor(ps0, 16);
    ps0 += __shfl_xor(ps0, 32);
    ps1 += __shfl_xor(ps1, 16);
    ps1 += __shfl_xor(ps1, 32);
    l0r += ps0;
    l1r += ps1;

    // ---- O += P @ V : P is LANE-LOCAL (sigma made A-frag = own sf regs) ----
    __builtin_amdgcn_s_setprio(1);
#pragma unroll
    for (int ks = 0; ks < 2; ++ks) {
      s16x8 pa0, pa1;
#pragma unroll
      for (int i = 0; i < 4; ++i) {
        pa0[i]     = __builtin_bit_cast(short, (__bf16)sf0[2 * ks][i]);
        pa0[i + 4] = __builtin_bit_cast(short, (__bf16)sf0[2 * ks + 1][i]);
        pa1[i]     = __builtin_bit_cast(short, (__bf16)sf1[2 * ks][i]);
        pa1[i + 4] = __builtin_bit_cast(short, (__bf16)sf1[2 * ks + 1][i]);
      }
      const int rbv = ks ? rbv1 : rbv0;
#pragma unroll
      for (int di = 0; di < 4; ++di) {
        const s16x8 vf = *reinterpret_cast<const s16x8*>(
            &smem[16384 + B * 4096 + di * 1024 + rbv]);
        oacc0[di] = MFMA16(pa0, vf, oacc0[di]);
        oacc1[di] = MFMA16(pa1, vf, oacc1[di]);
      }
    }
    __builtin_amdgcn_s_setprio(0);
  };

  ASTAGE(0);
  __syncthreads();
  for (int kt = 0; kt < SEQLEN / 64 - 2; kt += 2) {
    ASTAGE(1);
    process(0);
    __syncthreads();
    ASTAGE(0);
    process(1);
    __syncthreads();
  }
  ASTAGE(1);
  process(0);
  __syncthreads();
  process(1);

  // ---- epilogue: normalize (l lives in fr-domain -> shfl to 4g+r), write ----
  const int b = bh >> 4, h = bh & 15;
  const float inv0 = 1.0f / l0r, inv1 = 1.0f / l1r;
  float iv0[4], iv1[4];
#pragma unroll
  for (int r = 0; r < 4; ++r) {
    iv0[r] = __shfl(inv0, 4 * g + r);
    iv1[r] = __shfl(inv1, 4 * g + r);
  }
#pragma unroll
  for (int di = 0; di < 4; ++di)
#pragma unroll
    for (int r = 0; r < 4; ++r) {
      const int srow = q0 + w * 32 + 4 * g + r;
      const size_t o0 = ((size_t)b * SEQLEN + srow) * HDIM + h * 64 + di * 16 + fr;
      const size_t o1 = o0 + 16 * HDIM;  // qb=1 rows are +16
      const float v0 = oacc0[di][r] * iv0[r];
      const float v1 = oacc1[di][r] * iv1[r];
      const __bf16 hb0 = (__bf16)v0;
      const __bf16 hb1 = (__bf16)v1;
      OH[o0] = hb0;
      OL[o0] = (__bf16)(v0 - (float)hb0);
      OH[o1] = hb1;
      OL[o1] = (__bf16)(v1 - (float)hb1);
    }
#undef ASTAGE
}

// ---------------------------------------------------------------------------
// Fused ReLU + LayerNorm over rows of 1024. One block (256 thr) per row.
// ---------------------------------------------------------------------------
__global__ __launch_bounds__(256) void relu_ln_k(const float* __restrict__ X,
                                                 const float* __restrict__ gam,
                                                 const float* __restrict__ bta,
                                                 float* __restrict__ out) {
  __shared__ float red[8];
  const int row = blockIdx.x;
  const int tid = threadIdx.x;
  const int c = tid << 2;

  const float4 v = *reinterpret_cast<const float4*>(&X[(size_t)row * HDIM + c]);
  float x[4] = {fmaxf(v.x, 0.f), fmaxf(v.y, 0.f), fmaxf(v.z, 0.f), fmaxf(v.w, 0.f)};
  float sum = x[0] + x[1] + x[2] + x[3];
  float ss = x[0] * x[0] + x[1] * x[1] + x[2] * x[2] + x[3] * x[3];
#pragma unroll
  for (int off = 1; off < 64; off <<= 1) {
    sum += __shfl_xor(sum, off);
    ss += __shfl_xor(ss, off);
  }
  const int wid = tid >> 6;
  if ((tid & 63) == 0) {
    red[wid] = sum;
    red[4 + wid] = ss;
  }
  __syncthreads();
  sum = red[0] + red[1] + red[2] + red[3];
  ss = red[4] + red[5] + red[6] + red[7];
  const float mean = sum * (1.0f / HDIM);
  const float var = ss * (1.0f / HDIM) - mean * mean;
  const float rstd = rsqrtf(var + LN_EPS);

  const float4 gv = *reinterpret_cast<const float4*>(&gam[c]);
  const float4 bv = *reinterpret_cast<const float4*>(&bta[c]);
  float4 o;
  o.x = (x[0] - mean) * rstd * gv.x + bv.x;
  o.y = (x[1] - mean) * rstd * gv.y + bv.y;
  o.z = (x[2] - mean) * rstd * gv.z + bv.z;
  o.w = (x[3] - mean) * rstd * gv.w + bv.w;
  *reinterpret_cast<float4*>(&out[(size_t)row * HDIM + c]) = o;
}

// ---------------------------------------------------------------------------
// Launch. ws (128 MB):
//  [0,16M): wts hi (qw,kw,vw,ow @2MB) + wts lo (@2MB each)
//  [16,48M): QH,QL        -> later proj fp32 (32MB)
//  [48,80M): KH,KL
//  [80,96M): VtH
//  [96,128M): featH,featL -> later attnH,attnL
// ---------------------------------------------------------------------------
extern "C" void kernel_launch(void* const* d_in, const int* in_sizes, int n_in,
                              void* d_out, int out_size, void* d_ws, size_t ws_size,
                              hipStream_t stream) {
  const float* feat = (const float*)d_in[0];
  const float* qw = (const float*)d_in[1];
  const float* qb = (const float*)d_in[2];
  const float* kw = (const float*)d_in[3];
  const float* kb = (const float*)d_in[4];
  const float* vw = (const float*)d_in[5];
  const float* vb = (const float*)d_in[6];
  const float* ow = (const float*)d_in[7];
  const float* ob = (const float*)d_in[8];
  const float* ln_g = (const float*)d_in[9];
  const float* ln_b = (const float*)d_in[10];

  char* ws = (char*)d_ws;
  const size_t MB = 1u << 20;
  __bf16* qwH = (__bf16*)(ws + 0 * MB);
  __bf16* kwH = (__bf16*)(ws + 2 * MB);
  __bf16* vwH = (__bf16*)(ws + 4 * MB);
  __bf16* owH = (__bf16*)(ws + 6 * MB);
  __bf16* qwL = (__bf16*)(ws + 8 * MB);
  __bf16* kwL = (__bf16*)(ws + 10 * MB);
  __bf16* vwL = (__bf16*)(ws + 12 * MB);
  __bf16* owL = (__bf16*)(ws + 14 * MB);
  __bf16* QHp = (__bf16*)(ws + 16 * MB);
  __bf16* QLp = (__bf16*)(ws + 32 * MB);
  __bf16* KHp = (__bf16*)(ws + 48 * MB);
  __bf16* KLp = (__bf16*)(ws + 64 * MB);
  __bf16* VTp = (__bf16*)(ws + 80 * MB);
  __bf16* ftH = (__bf16*)(ws + 96 * MB);
  __bf16* ftL = (__bf16*)(ws + 112 * MB);
  __bf16* atH = ftH;  // reuse after feat dead
  __bf16* atL = ftL;
  float* proj = (float*)(ws + 16 * MB);  // reuse Q region after attention

  // splits
  split_k<<<(MROWS * HDIM / 4 + 255) / 256, 256, 0, stream>>>(feat, ftH, ftL,
                                                              MROWS * HDIM / 4);
  wsplit_k<<<dim3(HDIM * HDIM / 4 / 256, 4), 256, 0, stream>>>(
      qw, kw, vw, ow, qwH, qwL, kwH, kwL, vwH, vwL, owH, owL);

  const dim3 gg(MROWS / 128, HDIM / 128);
  gemm3p_k<0, 3><<<gg, 256, 0, stream>>>(ftH, ftL, qwH, qwL, qb, QSCALE, QHp, QLp, nullptr);
  gemm3p_k<0, 3><<<gg, 256, 0, stream>>>(ftH, ftL, kwH, kwL, kb, 1.0f, KHp, KLp, nullptr);
  gemm3p_k<1, 2><<<gg, 256, 0, stream>>>(ftH, ftL, vwH, vwL, vb, 1.0f, VTp, nullptr, nullptr);

  attn7_k<<<BATCH * NHEAD * (SEQLEN / 128), 256, 0, stream>>>(QHp, QLp, KHp, KLp,
                                                              VTp, atH, atL);

  gemm3p_k<2, 2><<<gg, 256, 0, stream>>>(atH, atL, owH, owL, ob, 1.0f, nullptr,
                                         nullptr, proj);

  relu_ln_k<<<MROWS, 256, 0, stream>>>(proj, ln_g, ln_b, (float*)d_out);
}